// Round 2
// baseline (711.561 us; speedup 1.0000x reference)
//
#include <hip/hip_runtime.h>
#include <math.h>

#define NN 256
#define HH 8
#define DD 64
#define BH 16
#define SCALER 0.125f

// workspace offsets (in floats)
#define REG     (BH*NN*DD)             // 262144, one of a/b/c/v1/v2
#define OFF_QKV 0
#define QKV_SZ  (5*REG)                // 1310720
#define MAT_SZ  (BH*NN*NN)             // 1048576
#define OFF_X   (QKV_SZ)
#define OFF_Y   (OFF_X + MAT_SZ)
#define OFF_Z   (OFF_Y + MAT_SZ)
#define OFF_MX  (OFF_Z + MAT_SZ)
#define OFF_MY  (OFF_MX + BH*NN)
#define OFF_MZ  (OFF_MY + 16)
#define KSPLIT  8
#define OFF_UP  (OFF_MZ + BH*NN)
#define UP_SZ   (KSPLIT*BH*NN*DD)      // 2097152
#define OFF_DN  (OFF_UP + UP_SZ)

// ---------------- K1: projection GEMM  y[r][o] = sum_c h[r][c]*W[o][c] ----------------
// writes directly into 5 regions [p][bh][n][d]
__global__ __launch_bounds__(256) void k_proj(const float* __restrict__ Hs,
                                              const float* __restrict__ W,
                                              float* __restrict__ qkv) {
  __shared__ float As[16][68]; // [k][m]
  __shared__ float Bs[16][68]; // [k][o]
  const int bx = blockIdx.x;   // o-tile (40)
  const int by = blockIdx.y;   // m-tile (8)
  const int tid = threadIdx.x;
  const int ri = tid >> 4, ci = tid & 15;
  const int o0 = bx * 64, m0 = by * 64;
  float acc[4][4] = {};
  for (int k0 = 0; k0 < 512; k0 += 16) {
    __syncthreads();
    {
      const int m = tid >> 2, kq = (tid & 3) * 4;
      float4 va = *(const float4*)&Hs[(m0 + m) * 512 + k0 + kq];
      As[kq + 0][m] = va.x; As[kq + 1][m] = va.y; As[kq + 2][m] = va.z; As[kq + 3][m] = va.w;
      float4 vb = *(const float4*)&W[(o0 + m) * 512 + k0 + kq];
      Bs[kq + 0][m] = vb.x; Bs[kq + 1][m] = vb.y; Bs[kq + 2][m] = vb.z; Bs[kq + 3][m] = vb.w;
    }
    __syncthreads();
#pragma unroll
    for (int kk = 0; kk < 16; ++kk) {
      float4 a = *(const float4*)&As[kk][ri * 4];
      float4 b = *(const float4*)&Bs[kk][ci * 4];
      acc[0][0] += a.x * b.x; acc[0][1] += a.x * b.y; acc[0][2] += a.x * b.z; acc[0][3] += a.x * b.w;
      acc[1][0] += a.y * b.x; acc[1][1] += a.y * b.y; acc[1][2] += a.y * b.z; acc[1][3] += a.y * b.w;
      acc[2][0] += a.z * b.x; acc[2][1] += a.z * b.y; acc[2][2] += a.z * b.z; acc[2][3] += a.z * b.w;
      acc[3][0] += a.w * b.x; acc[3][1] += a.w * b.y; acc[3][2] += a.w * b.z; acc[3][3] += a.w * b.w;
    }
  }
  const int p = o0 >> 9;            // which of the 5 outputs
  const int h = (o0 >> 6) & 7;      // head (fixed per 64-wide o tile)
  const int d0 = ci * 4;
#pragma unroll
  for (int l = 0; l < 4; ++l) {
    const int r = m0 + ri * 4 + l;
    const int b = r >> 8, n = r & 255;
    float* dst = qkv + p * REG + (b * 8 + h) * (NN * DD) + n * DD + d0;
    *(float4*)dst = make_float4(acc[l][0], acc[l][1], acc[l][2], acc[l][3]);
  }
}

// ---------------- K2: score matrices S = U * Wm^T * SCALER + pb --------------------
__global__ __launch_bounds__(256) void k_scores(const float* __restrict__ qkv,
                                                float* __restrict__ ws) {
  __shared__ float Us[32][68];
  __shared__ float Ws_[32][68];
  const int ms = blockIdx.z, bh = blockIdx.y;
  const int tr = blockIdx.x >> 3, tc = blockIdx.x & 7;
  const float* U; const float* Wm; float* O;
  if (ms == 0)      { U = qkv + 0 * REG; Wm = qkv + 1 * REG; O = ws + OFF_X; } // X = a.b
  else if (ms == 1) { U = qkv + 1 * REG; Wm = qkv + 2 * REG; O = ws + OFF_Y; } // Y = b.c
  else              { U = qkv + 2 * REG; Wm = qkv + 0 * REG; O = ws + OFF_Z; } // Z = c.a
  U  += bh * (NN * DD);
  Wm += bh * (NN * DD);
  O  += bh * (NN * NN);
  const int i0 = tr * 32, k0 = tc * 32;
  const int tid = threadIdx.x;
  {
    const int r = tid >> 3, d8 = (tid & 7) * 8;
    *(float4*)&Us[r][d8]      = *(const float4*)&U[(i0 + r) * DD + d8];
    *(float4*)&Us[r][d8 + 4]  = *(const float4*)&U[(i0 + r) * DD + d8 + 4];
    *(float4*)&Ws_[r][d8]     = *(const float4*)&Wm[(k0 + r) * DD + d8];
    *(float4*)&Ws_[r][d8 + 4] = *(const float4*)&Wm[(k0 + r) * DD + d8 + 4];
  }
  __syncthreads();
  const int ri = tid >> 4, ci = tid & 15;
  float a00 = 0.f, a01 = 0.f, a10 = 0.f, a11 = 0.f;
#pragma unroll
  for (int dd = 0; dd < 16; ++dd) {
    float4 u0 = *(const float4*)&Us[ri][dd * 4];
    float4 u1 = *(const float4*)&Us[ri + 16][dd * 4];
    float4 w0 = *(const float4*)&Ws_[ci][dd * 4];
    float4 w1 = *(const float4*)&Ws_[ci + 16][dd * 4];
    a00 += u0.x * w0.x + u0.y * w0.y + u0.z * w0.z + u0.w * w0.w;
    a01 += u0.x * w1.x + u0.y * w1.y + u0.z * w1.z + u0.w * w1.w;
    a10 += u1.x * w0.x + u1.y * w0.y + u1.z * w0.z + u1.w * w0.w;
    a11 += u1.x * w1.x + u1.y * w1.y + u1.z * w1.z + u1.w * w1.w;
  }
#define STORE_SC(accv, rr, cc) { \
    int row = (rr), col = (cc); \
    O[row * NN + col] = (accv) * SCALER + fminf((float)(col - row), 0.f); }
  STORE_SC(a00, i0 + ri,      k0 + ci)
  STORE_SC(a01, i0 + ri,      k0 + ci + 16)
  STORE_SC(a10, i0 + ri + 16, k0 + ci)
  STORE_SC(a11, i0 + ri + 16, k0 + ci + 16)
#undef STORE_SC
}

// ---------------- K3a: row max of X -> mx[bh*N + i] ----------------
__global__ __launch_bounds__(256) void k_rowmax(const float* __restrict__ Xb, float* __restrict__ mx) {
  const int wid = threadIdx.x >> 6, lane = threadIdx.x & 63;
  const int gr = blockIdx.x * 4 + wid;  // 0..4095
  float4 v = *(const float4*)&Xb[gr * 256 + lane * 4];
  float m = fmaxf(fmaxf(v.x, v.y), fmaxf(v.z, v.w));
#pragma unroll
  for (int off = 32; off; off >>= 1) m = fmaxf(m, __shfl_xor(m, off));
  if (lane == 0) mx[gr] = m;
}

// ---------------- K3b: global max of Y per bh -> my[bh] ----------------
__global__ __launch_bounds__(256) void k_gmax(const float* __restrict__ Yb, float* __restrict__ my) {
  const int bh = blockIdx.x, tid = threadIdx.x;
  const float4* p = (const float4*)(Yb + bh * (NN * NN));
  float m = -3.4e38f;
  for (int idx = tid; idx < 16384; idx += 256) {
    float4 v = p[idx];
    m = fmaxf(m, fmaxf(fmaxf(v.x, v.y), fmaxf(v.z, v.w)));
  }
#pragma unroll
  for (int off = 32; off; off >>= 1) m = fmaxf(m, __shfl_xor(m, off));
  __shared__ float red[4];
  if ((tid & 63) == 0) red[tid >> 6] = m;
  __syncthreads();
  if (tid == 0) my[bh] = fmaxf(fmaxf(red[0], red[1]), fmaxf(red[2], red[3]));
}

// ---------------- K3c: column max of Z over k -> mz[bh*N + i] ----------------
__global__ __launch_bounds__(256) void k_colmax(const float* __restrict__ Zb, float* __restrict__ mz) {
  const int bh = blockIdx.x, ic = blockIdx.y;
  const int il = threadIdx.x & 63, kp = threadIdx.x >> 6;
  const int i = ic * 64 + il;
  float m = -3.4e38f;
  for (int k = kp; k < 256; k += 4) m = fmaxf(m, Zb[bh * (NN * NN) + k * NN + i]);
  __shared__ float red[4][64];
  red[kp][il] = m;
  __syncthreads();
  if (kp == 0)
    mz[bh * NN + i] = fmaxf(fmaxf(red[0][il], red[1][il]), fmaxf(red[2][il], red[3][il]));
}

// ---------------- K4: in-place exp with the right max subtraction ----------------
__global__ __launch_bounds__(256) void k_exp(float* __restrict__ ws) {
  const int g = blockIdx.x * 256 + threadIdx.x;       // float4 id, 786432 total
  const int buf = g / 262144, rem = g % 262144;       // per-matrix float4 count = 262144
  const int bh = rem >> 14, rr = rem & 16383;
  const int row = rr >> 6, c4 = (rr & 63) * 4;
  float4* base = (float4*)(ws + (buf == 0 ? OFF_X : buf == 1 ? OFF_Y : OFF_Z));
  float4 v = base[rem];
  if (buf == 0) {
    float s = ws[OFF_MX + bh * NN + row];
    v.x = expf(v.x - s); v.y = expf(v.y - s); v.z = expf(v.z - s); v.w = expf(v.w - s);
  } else if (buf == 1) {
    float s = ws[OFF_MY + bh];
    v.x = expf(v.x - s); v.y = expf(v.y - s); v.z = expf(v.z - s); v.w = expf(v.w - s);
  } else {
    float4 s = *(const float4*)&ws[OFF_MZ + bh * NN + c4];
    v.x = expf(v.x - s.x); v.y = expf(v.y - s.y); v.z = expf(v.z - s.z); v.w = expf(v.w - s.w);
  }
  base[rem] = v;
}

// ---------------- K5: fused triple contraction ----------------
// up[i][d]  = sum_k Z[k][i]*v2[k][d] * sum_j X[i][j]*Y[j][k]*v1[j][d]
// down[i]   = sum_k Z[k][i] * sum_j X[i][j]*Y[j][k]
// launch_bounds(256,2): accumulator state ~80 floats + temps; the ,4 variant
// would cap the allocator at 128 VGPR and risk spilling the C array.
__global__ __launch_bounds__(256, 2) void k_heavy(const float* __restrict__ ws_in,
                                                  float* __restrict__ upP,
                                                  float* __restrict__ dnP) {
  const int ks = blockIdx.x;   // 0..7  k-split
  const int it = blockIdx.y;   // 0..7  i-tile (32 rows)
  const int bh = blockIdx.z;   // 0..15
  const int i0 = it * 32;
  const int tid = threadIdx.x;
  const int il = tid >> 3;     // 0..31 local i
  const int dg = tid & 7;      // d-octet

  __shared__ float Xs[32][36];
  __shared__ float Ys[32][8];
  __shared__ float v1s[32][64];
  __shared__ float Zs[8][36];
  __shared__ float v2s[8][64];

  const float* Xp = ws_in + OFF_X + bh * (NN * NN);
  const float* Yp = ws_in + OFF_Y + bh * (NN * NN);
  const float* Zp = ws_in + OFF_Z + bh * (NN * NN);
  const float* v1 = ws_in + OFF_QKV + 3 * REG + bh * (NN * DD);
  const float* v2 = ws_in + OFF_QKV + 4 * REG + bh * (NN * DD);

  float up[8] = {0.f, 0.f, 0.f, 0.f, 0.f, 0.f, 0.f, 0.f};
  float down_acc = 0.f;

  for (int kt = 0; kt < 4; ++kt) {
    const int k0 = (ks * 4 + kt) * 8;
    __syncthreads();  // protect Zs/v2s from previous epilogue readers
    if (tid < 64) {
      const int kk = tid >> 3, i4 = (tid & 7) * 4;
      *(float4*)&Zs[kk][i4] = *(const float4*)&Zp[(k0 + kk) * NN + i0 + i4];
    } else if (tid < 192) {
      const int t = tid - 64, kk = t >> 4, d4 = (t & 15) * 4;
      *(float4*)&v2s[kk][d4] = *(const float4*)&v2[(k0 + kk) * DD + d4];
    }
    float C[8][8] = {};
    float S[8] = {0.f, 0.f, 0.f, 0.f, 0.f, 0.f, 0.f, 0.f};

    for (int jt = 0; jt < 8; ++jt) {
      const int j0 = jt * 32;
      __syncthreads();
      {
        const int ii = tid >> 3, j4 = (tid & 7) * 4;
        *(float4*)&Xs[ii][j4] = *(const float4*)&Xp[(i0 + ii) * NN + j0 + j4];
      }
      if (tid < 64) {
        const int jj = tid >> 1, kq = (tid & 1) * 4;
        *(float4*)&Ys[jj][kq] = *(const float4*)&Yp[(j0 + jj) * NN + k0 + kq];
      }
      {
        const int jj = tid >> 3, d8 = (tid & 7) * 8;
        *(float4*)&v1s[jj][d8]     = *(const float4*)&v1[(j0 + jj) * DD + d8];
        *(float4*)&v1s[jj][d8 + 4] = *(const float4*)&v1[(j0 + jj) * DD + d8 + 4];
      }
      __syncthreads();
#pragma unroll 4
      for (int jj = 0; jj < 32; ++jj) {
        const float xv = Xs[il][jj];
        const float4 y0 = *(const float4*)&Ys[jj][0];
        const float4 y1 = *(const float4*)&Ys[jj][4];
        const float4 a0 = *(const float4*)&v1s[jj][dg * 8];
        const float4 a1 = *(const float4*)&v1s[jj][dg * 8 + 4];
#define KSTEP(kk, yv) { float t = xv * (yv); S[kk] += t; \
        C[kk][0] += t * a0.x; C[kk][1] += t * a0.y; C[kk][2] += t * a0.z; C[kk][3] += t * a0.w; \
        C[kk][4] += t * a1.x; C[kk][5] += t * a1.y; C[kk][6] += t * a1.z; C[kk][7] += t * a1.w; }
        KSTEP(0, y0.x) KSTEP(1, y0.y) KSTEP(2, y0.z) KSTEP(3, y0.w)
        KSTEP(4, y1.x) KSTEP(5, y1.y) KSTEP(6, y1.z) KSTEP(7, y1.w)
#undef KSTEP
      }
    }
    // epilogue: contract C,S with Z and v2 for this k-tile
#pragma unroll
    for (int kk = 0; kk < 8; ++kk) {
      const float zv = Zs[kk][il];
      down_acc += zv * S[kk];
      const float4 w0 = *(const float4*)&v2s[kk][dg * 8];
      const float4 w1 = *(const float4*)&v2s[kk][dg * 8 + 4];
      float c;
      c = zv * C[kk][0]; up[0] += c * w0.x;
      c = zv * C[kk][1]; up[1] += c * w0.y;
      c = zv * C[kk][2]; up[2] += c * w0.z;
      c = zv * C[kk][3]; up[3] += c * w0.w;
      c = zv * C[kk][4]; up[4] += c * w1.x;
      c = zv * C[kk][5]; up[5] += c * w1.y;
      c = zv * C[kk][6]; up[6] += c * w1.z;
      c = zv * C[kk][7]; up[7] += c * w1.w;
    }
  }
  const int i = i0 + il;
  float* ud = upP + ((ks * BH + bh) * NN + i) * DD + dg * 8;
  *(float4*)ud       = make_float4(up[0], up[1], up[2], up[3]);
  *(float4*)(ud + 4) = make_float4(up[4], up[5], up[6], up[7]);
  if (dg == 0) dnP[(ks * BH + bh) * NN + i] = down_acc;
}

// ---------------- K6: combine partials, divide, write output layout [b][n][h*64+d] ----------------
__global__ __launch_bounds__(256) void k_final(const float* __restrict__ ws_in, float* __restrict__ out) {
  const int g = blockIdx.x * 256 + threadIdx.x;  // float4 id, 65536 total
  const int e0 = g * 4;
  const int c = e0 & 511, n = (e0 >> 9) & 255, b = e0 >> 17;
  const int h = c >> 6, d = c & 63;
  const int bh = b * 8 + h;
  const float* upP = ws_in + OFF_UP;
  const float* dnP = ws_in + OFF_DN;
  float4 acc = make_float4(0.f, 0.f, 0.f, 0.f);
  float dn = 0.f;
#pragma unroll
  for (int ks = 0; ks < KSPLIT; ++ks) {
    const float4 u = *(const float4*)&upP[((ks * BH + bh) * NN + n) * DD + d];
    acc.x += u.x; acc.y += u.y; acc.z += u.z; acc.w += u.w;
    dn += dnP[(ks * BH + bh) * NN + n];
  }
  const float inv = 1.f / (dn + 1e-9f);
  acc.x *= inv; acc.y *= inv; acc.z *= inv; acc.w *= inv;
  *(float4*)&out[e0] = acc;
}

extern "C" void kernel_launch(void* const* d_in, const int* in_sizes, int n_in,
                              void* d_out, int out_size, void* d_ws, size_t ws_size,
                              hipStream_t stream) {
  (void)in_sizes; (void)n_in; (void)out_size; (void)ws_size;
  const float* hidden = (const float*)d_in[0];
  const float* W      = (const float*)d_in[1];
  float* ws  = (float*)d_ws;
  float* out = (float*)d_out;

  k_proj<<<dim3(40, 8), 256, 0, stream>>>(hidden, W, ws + OFF_QKV);
  k_scores<<<dim3(64, BH, 3), 256, 0, stream>>>(ws + OFF_QKV, ws);
  k_rowmax<<<dim3(1024), 256, 0, stream>>>(ws + OFF_X, ws + OFF_MX);
  k_gmax<<<dim3(16), 256, 0, stream>>>(ws + OFF_Y, ws + OFF_MY);
  k_colmax<<<dim3(16, 4), 256, 0, stream>>>(ws + OFF_Z, ws + OFF_MZ);
  k_exp<<<dim3(3072), 256, 0, stream>>>(ws);
  k_heavy<<<dim3(KSPLIT, 8, BH), 256, 0, stream>>>(ws, ws + OFF_UP, ws + OFF_DN);
  k_final<<<dim3(256), 256, 0, stream>>>(ws, out);
}

// Round 5
// 202.966 us; speedup vs baseline: 3.5058x; 3.5058x over previous
//
#include <hip/hip_runtime.h>
#include <math.h>

#define NN 256
#define HH 8
#define DD 64
#define BH 16
#define SCALER 0.125f

#define REG     (BH*NN*DD)             // 262144 floats
#define MAT_SZ  (BH*NN*NN)             // 1048576 floats
// fp16 buffers overlay the dead a/b/c projections (only v1,v2 at 3*REG,4*REG live on)
#define OFF_XH  0                      // fp16 [bh][i][j]   (524288 floats of space)
#define OFF_V1T 524288                 // fp16 [bh][d][j]   (131072 floats of space)
#define OFF_QKV 0
#define OFF_X   1310720
#define OFF_Y   (OFF_X + MAT_SZ)
#define OFF_Z   (OFF_Y + MAT_SZ)
#define OFF_MX  (OFF_Z + MAT_SZ)
#define OFF_MY  (OFF_MX + BH*NN)
#define OFF_MZ  (OFF_MY + 16)
#define OFF_YT  4464656                // fp16 [bh][k][j]
#define OFF_V2T 4988944                // fp32 [bh][d][k]
#define KB      4
#define OFF_UP  5251088                // fp32 [kb][bh][i][d]
#define OFF_DN  6299664                // fp32 [kb][bh][i]
// end 6316048 floats = 25.3 MB (< round-2's proven 26.4 MB footprint)

typedef _Float16 f16x8 __attribute__((ext_vector_type(8)));
typedef _Float16 f16x4 __attribute__((ext_vector_type(4)));
typedef float    f32x4 __attribute__((ext_vector_type(4)));

// ---------------- K1: projection GEMM (unchanged, validated) ----------------
__global__ __launch_bounds__(256) void k_proj(const float* __restrict__ Hs,
                                              const float* __restrict__ W,
                                              float* __restrict__ qkv) {
  __shared__ float As[16][68];
  __shared__ float Bs[16][68];
  const int bx = blockIdx.x, by = blockIdx.y;
  const int tid = threadIdx.x;
  const int ri = tid >> 4, ci = tid & 15;
  const int o0 = bx * 64, m0 = by * 64;
  float acc[4][4] = {};
  for (int k0 = 0; k0 < 512; k0 += 16) {
    __syncthreads();
    {
      const int m = tid >> 2, kq = (tid & 3) * 4;
      float4 va = *(const float4*)&Hs[(m0 + m) * 512 + k0 + kq];
      As[kq + 0][m] = va.x; As[kq + 1][m] = va.y; As[kq + 2][m] = va.z; As[kq + 3][m] = va.w;
      float4 vb = *(const float4*)&W[(o0 + m) * 512 + k0 + kq];
      Bs[kq + 0][m] = vb.x; Bs[kq + 1][m] = vb.y; Bs[kq + 2][m] = vb.z; Bs[kq + 3][m] = vb.w;
    }
    __syncthreads();
#pragma unroll
    for (int kk = 0; kk < 16; ++kk) {
      float4 a = *(const float4*)&As[kk][ri * 4];
      float4 b = *(const float4*)&Bs[kk][ci * 4];
      acc[0][0] += a.x * b.x; acc[0][1] += a.x * b.y; acc[0][2] += a.x * b.z; acc[0][3] += a.x * b.w;
      acc[1][0] += a.y * b.x; acc[1][1] += a.y * b.y; acc[1][2] += a.y * b.z; acc[1][3] += a.y * b.w;
      acc[2][0] += a.z * b.x; acc[2][1] += a.z * b.y; acc[2][2] += a.z * b.z; acc[2][3] += a.z * b.w;
      acc[3][0] += a.w * b.x; acc[3][1] += a.w * b.y; acc[3][2] += a.w * b.z; acc[3][3] += a.w * b.w;
    }
  }
  const int p = o0 >> 9;
  const int h = (o0 >> 6) & 7;
  const int d0 = ci * 4;
#pragma unroll
  for (int l = 0; l < 4; ++l) {
    const int r = m0 + ri * 4 + l;
    const int b = r >> 8, n = r & 255;
    float* dst = qkv + p * REG + (b * 8 + h) * (NN * DD) + n * DD + d0;
    *(float4*)dst = make_float4(acc[l][0], acc[l][1], acc[l][2], acc[l][3]);
  }
}

// ---------------- K2: score matrices (unchanged, validated) ----------------
__global__ __launch_bounds__(256) void k_scores(const float* __restrict__ qkv,
                                                float* __restrict__ ws) {
  __shared__ float Us[32][68];
  __shared__ float Ws_[32][68];
  const int ms = blockIdx.z, bh = blockIdx.y;
  const int tr = blockIdx.x >> 3, tc = blockIdx.x & 7;
  const float* U; const float* Wm; float* O;
  if (ms == 0)      { U = qkv + 0 * REG; Wm = qkv + 1 * REG; O = ws + OFF_X; }
  else if (ms == 1) { U = qkv + 1 * REG; Wm = qkv + 2 * REG; O = ws + OFF_Y; }
  else              { U = qkv + 2 * REG; Wm = qkv + 0 * REG; O = ws + OFF_Z; }
  U  += bh * (NN * DD);
  Wm += bh * (NN * DD);
  O  += bh * (NN * NN);
  const int i0 = tr * 32, k0 = tc * 32;
  const int tid = threadIdx.x;
  {
    const int r = tid >> 3, d8 = (tid & 7) * 8;
    *(float4*)&Us[r][d8]      = *(const float4*)&U[(i0 + r) * DD + d8];
    *(float4*)&Us[r][d8 + 4]  = *(const float4*)&U[(i0 + r) * DD + d8 + 4];
    *(float4*)&Ws_[r][d8]     = *(const float4*)&Wm[(k0 + r) * DD + d8];
    *(float4*)&Ws_[r][d8 + 4] = *(const float4*)&Wm[(k0 + r) * DD + d8 + 4];
  }
  __syncthreads();
  const int ri = tid >> 4, ci = tid & 15;
  float a00 = 0.f, a01 = 0.f, a10 = 0.f, a11 = 0.f;
#pragma unroll
  for (int dd = 0; dd < 16; ++dd) {
    float4 u0 = *(const float4*)&Us[ri][dd * 4];
    float4 u1 = *(const float4*)&Us[ri + 16][dd * 4];
    float4 w0 = *(const float4*)&Ws_[ci][dd * 4];
    float4 w1 = *(const float4*)&Ws_[ci + 16][dd * 4];
    a00 += u0.x * w0.x + u0.y * w0.y + u0.z * w0.z + u0.w * w0.w;
    a01 += u0.x * w1.x + u0.y * w1.y + u0.z * w1.z + u0.w * w1.w;
    a10 += u1.x * w0.x + u1.y * w0.y + u1.z * w0.z + u1.w * w0.w;
    a11 += u1.x * w1.x + u1.y * w1.y + u1.z * w1.z + u1.w * w1.w;
  }
#define STORE_SC(accv, rr, cc) { \
    int row = (rr), col = (cc); \
    O[row * NN + col] = (accv) * SCALER + fminf((float)(col - row), 0.f); }
  STORE_SC(a00, i0 + ri,      k0 + ci)
  STORE_SC(a01, i0 + ri,      k0 + ci + 16)
  STORE_SC(a10, i0 + ri + 16, k0 + ci)
  STORE_SC(a11, i0 + ri + 16, k0 + ci + 16)
#undef STORE_SC
}

// ---------------- K3a/b/c: maxes (unchanged) ----------------
__global__ __launch_bounds__(256) void k_rowmax(const float* __restrict__ Xb, float* __restrict__ mx) {
  const int wid = threadIdx.x >> 6, lane = threadIdx.x & 63;
  const int gr = blockIdx.x * 4 + wid;
  float4 v = *(const float4*)&Xb[gr * 256 + lane * 4];
  float m = fmaxf(fmaxf(v.x, v.y), fmaxf(v.z, v.w));
#pragma unroll
  for (int off = 32; off; off >>= 1) m = fmaxf(m, __shfl_xor(m, off));
  if (lane == 0) mx[gr] = m;
}

__global__ __launch_bounds__(256) void k_gmax(const float* __restrict__ Yb, float* __restrict__ my) {
  const int bh = blockIdx.x, tid = threadIdx.x;
  const float4* p = (const float4*)(Yb + bh * (NN * NN));
  float m = -3.4e38f;
  for (int idx = tid; idx < 16384; idx += 256) {
    float4 v = p[idx];
    m = fmaxf(m, fmaxf(fmaxf(v.x, v.y), fmaxf(v.z, v.w)));
  }
#pragma unroll
  for (int off = 32; off; off >>= 1) m = fmaxf(m, __shfl_xor(m, off));
  __shared__ float red[4];
  if ((tid & 63) == 0) red[tid >> 6] = m;
  __syncthreads();
  if (tid == 0) my[bh] = fmaxf(fmaxf(red[0], red[1]), fmaxf(red[2], red[3]));
}

__global__ __launch_bounds__(256) void k_colmax(const float* __restrict__ Zb, float* __restrict__ mz) {
  const int bh = blockIdx.x, ic = blockIdx.y;
  const int il = threadIdx.x & 63, kp = threadIdx.x >> 6;
  const int i = ic * 64 + il;
  float m = -3.4e38f;
  for (int k = kp; k < 256; k += 4) m = fmaxf(m, Zb[bh * (NN * NN) + k * NN + i]);
  __shared__ float red[4][64];
  red[kp][il] = m;
  __syncthreads();
  if (kp == 0)
    mz[bh * NN + i] = fmaxf(fmaxf(red[0][il], red[1][il]), fmaxf(red[2][il], red[3][il]));
}

// ---------------- K4: exp (unchanged) ----------------
__global__ __launch_bounds__(256) void k_exp(float* __restrict__ ws) {
  const int g = blockIdx.x * 256 + threadIdx.x;
  const int buf = g / 262144, rem = g % 262144;
  const int bh = rem >> 14, rr = rem & 16383;
  const int row = rr >> 6, c4 = (rr & 63) * 4;
  float4* base = (float4*)(ws + (buf == 0 ? OFF_X : buf == 1 ? OFF_Y : OFF_Z));
  float4 v = base[rem];
  if (buf == 0) {
    float s = ws[OFF_MX + bh * NN + row];
    v.x = expf(v.x - s); v.y = expf(v.y - s); v.z = expf(v.z - s); v.w = expf(v.w - s);
  } else if (buf == 1) {
    float s = ws[OFF_MY + bh];
    v.x = expf(v.x - s); v.y = expf(v.y - s); v.z = expf(v.z - s); v.w = expf(v.w - s);
  } else {
    float4 s = *(const float4*)&ws[OFF_MZ + bh * NN + c4];
    v.x = expf(v.x - s.x); v.y = expf(v.y - s.y); v.z = expf(v.z - s.z); v.w = expf(v.w - s.w);
  }
  base[rem] = v;
}

// ---------------- K4b: fp16 conversions + transposes ----------------
// blk 0..255: Xh straight | 256..511: Yt transpose | 512..575: v1t | 576..639: v2t
__global__ __launch_bounds__(256) void k_cvt(float* __restrict__ ws) {
  __shared__ float T[64][65];
  const int blk = blockIdx.x, tid = threadIdx.x;
  if (blk < 256) {
    const float* X = ws + OFF_X;
    _Float16* Xh = (_Float16*)(ws + OFF_XH);
    const int base = (blk * 256 + tid) * 16;
#pragma unroll
    for (int q = 0; q < 4; ++q) {
      float4 v = *(const float4*)&X[base + q * 4];
      f16x4 o = {(_Float16)v.x, (_Float16)v.y, (_Float16)v.z, (_Float16)v.w};
      *(f16x4*)((_Float16*)&Xh[base + q * 4]) = o;
    }
  } else if (blk < 512) {
    const int b2 = blk - 256;
    const int bh = b2 >> 4, jt = (b2 >> 2) & 3, kt = b2 & 3;
    const float* Y = ws + OFF_Y + bh * 65536;
    _Float16* Yt = (_Float16*)(ws + OFF_YT) + bh * 65536;
    const int j0 = jt * 64, k0 = kt * 64;
#pragma unroll 4
    for (int p = 0; p < 16; ++p) {
      const int idx = p * 256 + tid, r = idx >> 6, c = idx & 63;
      T[r][c] = Y[(j0 + r) * 256 + k0 + c];
    }
    __syncthreads();
#pragma unroll 4
    for (int p = 0; p < 16; ++p) {
      const int idx = p * 256 + tid, r = idx >> 6, c = idx & 63;
      Yt[(k0 + r) * 256 + j0 + c] = (_Float16)T[c][r];
    }
  } else if (blk < 576) {
    const int b2 = blk - 512;
    const int bh = b2 >> 2, jt = b2 & 3;
    const float* v1 = ws + OFF_QKV + 3 * REG + bh * 16384;
    _Float16* v1t = (_Float16*)(ws + OFF_V1T) + bh * 16384;
    const int j0 = jt * 64;
#pragma unroll 4
    for (int p = 0; p < 16; ++p) {
      const int idx = p * 256 + tid, r = idx >> 6, c = idx & 63;
      T[r][c] = v1[(j0 + r) * 64 + c];
    }
    __syncthreads();
#pragma unroll 4
    for (int p = 0; p < 16; ++p) {
      const int idx = p * 256 + tid, r = idx >> 6, c = idx & 63;   // r=d, c=j-local
      v1t[r * 256 + j0 + c] = (_Float16)T[c][r];
    }
  } else {
    const int b2 = blk - 576;
    const int bh = b2 >> 2, kt = b2 & 3;
    const float* v2 = ws + OFF_QKV + 4 * REG + bh * 16384;
    float* v2t = ws + OFF_V2T + bh * 16384;
    const int k0 = kt * 64;
#pragma unroll 4
    for (int p = 0; p < 16; ++p) {
      const int idx = p * 256 + tid, r = idx >> 6, c = idx & 63;
      T[r][c] = v2[(k0 + r) * 64 + c];
    }
    __syncthreads();
#pragma unroll 4
    for (int p = 0; p < 16; ++p) {
      const int idx = p * 256 + tid, r = idx >> 6, c = idx & 63;   // r=d, c=k-local
      v2t[r * 256 + k0 + c] = T[c][r];
    }
  }
}

// ---------------- K5: MFMA triple contraction ----------------
// Per d: D_d[k][i] = sum_j (Y[j][k]*v1[j][d]) * X[i][j]  via mfma_f32_16x16x32_f16
//   A-frag (M=k): lane row k=l&15, cols j=(l>>4)*8+m  -> Yt[k][j] 16B reads
//   B-frag (N=i): lane col i=l&15, rows j=(l>>4)*8+m  -> Xh[i][j] 16B reads
//   D: col i=l&15, row k=(l>>4)*4+r  (m89-verified layout)
// then up[i][d] += sum_k D*Z[k][i]*v2[k][d] (4 in-lane k + shfl over groups).
// down rides as a 65th slot (v1=1, v2=1).
__global__ __launch_bounds__(512) void k_heavy(const float* __restrict__ ws,
                                               float* __restrict__ upP,
                                               float* __restrict__ dnP) {
  const int kb = blockIdx.x, ib = blockIdx.y, bh = blockIdx.z;
  const int k0 = kb * 64, i0 = ib * 64;
  const int tid = threadIdx.x;
  const int w = tid >> 6, lane = tid & 63;
  const int k16 = w & 3, ihalf = w >> 2;
  const int li = lane & 15, grp = lane >> 4;

  __shared__ _Float16 v1s[64 * 256];   // 32 KB
  __shared__ float v2s[64 * 64];       // 16 KB
  __shared__ float up_lds[64][68];     // 17.4 KB, pad 68 breaks bank alignment
  __shared__ float dn_lds[64];

  const _Float16* Xh  = (const _Float16*)(ws + OFF_XH);
  const _Float16* Yt  = (const _Float16*)(ws + OFF_YT);
  const _Float16* v1t = (const _Float16*)(ws + OFF_V1T);
  const float*    v2t = ws + OFF_V2T;
  const float*    Zp  = ws + OFF_Z + bh * 65536;

  // stage v1t[bh] slice (32 KB) and v2t[bh][:, k0:k0+64] (16 KB) into LDS
  {
    const float4* src = (const float4*)(v1t + bh * 16384);
    float4* dst = (float4*)v1s;
    for (int t = tid; t < 2048; t += 512) dst[t] = src[t];
  }
  {
    const int d = tid >> 3, kq = (tid & 7) * 8;
    const float* s = v2t + bh * 16384 + d * 256 + k0 + kq;
    *(float4*)&v2s[d * 64 + kq]     = *(const float4*)s;
    *(float4*)&v2s[d * 64 + kq + 4] = *(const float4*)(s + 4);
  }
  for (int t = tid; t < 64 * 68; t += 512) ((float*)up_lds)[t] = 0.f;
  if (tid < 64) dn_lds[tid] = 0.f;

  // hoist fragments (d-independent) into registers
  f16x8 Yf[8];
  {
    const _Float16* yb = Yt + (long)bh * 65536 + (k0 + k16 * 16 + li) * 256 + grp * 8;
#pragma unroll
    for (int js = 0; js < 8; ++js) Yf[js] = *(const f16x8*)(yb + js * 32);
  }
  f16x8 Xf0[8], Xf1[8];
  {
    const _Float16* xb0 = Xh + (long)bh * 65536 + (i0 + (ihalf * 2 + 0) * 16 + li) * 256 + grp * 8;
    const _Float16* xb1 = Xh + (long)bh * 65536 + (i0 + (ihalf * 2 + 1) * 16 + li) * 256 + grp * 8;
#pragma unroll
    for (int js = 0; js < 8; ++js) { Xf0[js] = *(const f16x8*)(xb0 + js * 32); Xf1[js] = *(const f16x8*)(xb1 + js * 32); }
  }
  float Zr0[4], Zr1[4];
#pragma unroll
  for (int r = 0; r < 4; ++r) {
    const int kk = (k0 + k16 * 16 + grp * 4 + r) * 256 + i0;
    Zr0[r] = Zp[kk + (ihalf * 2 + 0) * 16 + li];
    Zr1[r] = Zp[kk + (ihalf * 2 + 1) * 16 + li];
  }

  __syncthreads();

  const int ir0 = (ihalf * 2 + 0) * 16 + li;
  const int ir1 = (ihalf * 2 + 1) * 16 + li;

  for (int it = 0; it < 64; ++it) {
    f32x4 acc0 = {0.f, 0.f, 0.f, 0.f}, acc1 = {0.f, 0.f, 0.f, 0.f};
#pragma unroll
    for (int js = 0; js < 8; ++js) {
      f16x8 vf = *(const f16x8*)&v1s[it * 256 + js * 32 + grp * 8];
      f16x8 ad = Yf[js] * vf;                         // A_d = Y ∘ v1_d  (v_pk_mul_f16)
      acc0 = __builtin_amdgcn_mfma_f32_16x16x32_f16(ad, Xf0[js], acc0, 0, 0, 0);
      acc1 = __builtin_amdgcn_mfma_f32_16x16x32_f16(ad, Xf1[js], acc1, 0, 0, 0);
    }
    f32x4 w2 = *(const f32x4*)&v2s[it * 64 + k16 * 16 + grp * 4];
    float s0 = (acc0[0] * Zr0[0]) * w2[0] + (acc0[1] * Zr0[1]) * w2[1]
             + (acc0[2] * Zr0[2]) * w2[2] + (acc0[3] * Zr0[3]) * w2[3];
    float s1 = (acc1[0] * Zr1[0]) * w2[0] + (acc1[1] * Zr1[1]) * w2[1]
             + (acc1[2] * Zr1[2]) * w2[2] + (acc1[3] * Zr1[3]) * w2[3];
    s0 += __shfl_xor(s0, 16); s0 += __shfl_xor(s0, 32);
    s1 += __shfl_xor(s1, 16); s1 += __shfl_xor(s1, 32);
    if (lane < 16) {
      atomicAdd(&up_lds[ir0][it], s0);
      atomicAdd(&up_lds[ir1][it], s1);
    }
  }
  { // down slot: A = Y (v1 == 1), v2 == 1
    f32x4 acc0 = {0.f, 0.f, 0.f, 0.f}, acc1 = {0.f, 0.f, 0.f, 0.f};
#pragma unroll
    for (int js = 0; js < 8; ++js) {
      acc0 = __builtin_amdgcn_mfma_f32_16x16x32_f16(Yf[js], Xf0[js], acc0, 0, 0, 0);
      acc1 = __builtin_amdgcn_mfma_f32_16x16x32_f16(Yf[js], Xf1[js], acc1, 0, 0, 0);
    }
    float s0 = acc0[0] * Zr0[0] + acc0[1] * Zr0[1] + acc0[2] * Zr0[2] + acc0[3] * Zr0[3];
    float s1 = acc1[0] * Zr1[0] + acc1[1] * Zr1[1] + acc1[2] * Zr1[2] + acc1[3] * Zr1[3];
    s0 += __shfl_xor(s0, 16); s0 += __shfl_xor(s0, 32);
    s1 += __shfl_xor(s1, 16); s1 += __shfl_xor(s1, 32);
    if (lane < 16) {
      atomicAdd(&dn_lds[ir0], s0);
      atomicAdd(&dn_lds[ir1], s1);
    }
  }
  __syncthreads();
  {
    const int il = tid >> 3, dq = (tid & 7) * 8;
    float* dst = upP + ((long)((kb * 16 + bh) * 256) + i0 + il) * 64 + dq;
    *(float4*)dst       = *(const float4*)&up_lds[il][dq];
    *(float4*)(dst + 4) = *(const float4*)&up_lds[il][dq + 4];
  }
  if (tid < 64) dnP[(kb * 16 + bh) * 256 + i0 + tid] = dn_lds[tid];
}

// ---------------- K6: combine 4 k-partials, divide, write [b][n][h*64+d] ----------------
__global__ __launch_bounds__(256) void k_final(const float* __restrict__ ws_in, float* __restrict__ out) {
  const int g = blockIdx.x * 256 + threadIdx.x;  // float4 id, 65536 total
  const int e0 = g * 4;
  const int c = e0 & 511, n = (e0 >> 9) & 255, b = e0 >> 17;
  const int h = c >> 6, d = c & 63;
  const int bh = b * 8 + h;
  const float* upP = ws_in + OFF_UP;
  const float* dnP = ws_in + OFF_DN;
  float4 acc = make_float4(0.f, 0.f, 0.f, 0.f);
  float dn = 0.f;
#pragma unroll
  for (int ks = 0; ks < KB; ++ks) {
    const float4 u = *(const float4*)&upP[((ks * 16 + bh) * 256 + n) * 64 + d];
    acc.x += u.x; acc.y += u.y; acc.z += u.z; acc.w += u.w;
    dn += dnP[(ks * 16 + bh) * 256 + n];
  }
  const float inv = 1.f / (dn + 1e-9f);
  acc.x *= inv; acc.y *= inv; acc.z *= inv; acc.w *= inv;
  *(float4*)&out[e0] = acc;
}

extern "C" void kernel_launch(void* const* d_in, const int* in_sizes, int n_in,
                              void* d_out, int out_size, void* d_ws, size_t ws_size,
                              hipStream_t stream) {
  (void)in_sizes; (void)n_in; (void)out_size; (void)ws_size;
  const float* hidden = (const float*)d_in[0];
  const float* W      = (const float*)d_in[1];
  float* ws  = (float*)d_ws;
  float* out = (float*)d_out;

  k_proj<<<dim3(40, 8), 256, 0, stream>>>(hidden, W, ws + OFF_QKV);
  k_scores<<<dim3(64, BH, 3), 256, 0, stream>>>(ws + OFF_QKV, ws);
  k_rowmax<<<dim3(1024), 256, 0, stream>>>(ws + OFF_X, ws + OFF_MX);
  k_gmax<<<dim3(16), 256, 0, stream>>>(ws + OFF_Y, ws + OFF_MY);
  k_colmax<<<dim3(16, 4), 256, 0, stream>>>(ws + OFF_Z, ws + OFF_MZ);
  k_exp<<<dim3(3072), 256, 0, stream>>>(ws);
  k_cvt<<<dim3(640), 256, 0, stream>>>(ws);
  k_heavy<<<dim3(KB, 4, BH), 512, 0, stream>>>(ws, ws + OFF_UP, ws + OFF_DN);
  k_final<<<dim3(256), 256, 0, stream>>>(ws, out);
}

// Round 6
// 191.390 us; speedup vs baseline: 3.7179x; 1.0605x over previous
//
#include <hip/hip_runtime.h>
#include <math.h>

#define NN 256
#define HH 8
#define DD 64
#define BH 16
#define SCALER 0.125f

#define REG     (BH*NN*DD)             // 262144 floats
#define MAT_SZ  (BH*NN*NN)             // 1048576 floats
// fp16 buffers overlay the dead a/b/c projections (only v1,v2 at 3*REG,4*REG live on)
#define OFF_XH  0                      // fp16 [bh][i][j]
#define OFF_V1T 524288                 // fp16 [bh][d][j]
#define OFF_QKV 0
#define OFF_X   1310720
#define OFF_Y   (OFF_X + MAT_SZ)
#define OFF_Z   (OFF_Y + MAT_SZ)
#define OFF_MX  (OFF_Z + MAT_SZ)       // 4096
#define OFF_MY  (OFF_MX + BH*NN)       // 16
#define OFF_MZ  (OFF_MY + 16)          // 4096
#define OFF_YT  4464656                // fp16 [bh][k][j]
#define OFF_V2T 4988944                // fp32 [bh][d][k]
#define KB      4
#define OFF_UP  5251088                // fp32 [kb][bh][i][d]
#define OFF_DN  6299664                // fp32 [kb][bh][i]  (16384)
#define OFF_YR  6316048                // fp32 yrow[4096]
// end 6320144 floats = 25.3 MB (< round-2's proven 25.33 MB footprint)

typedef _Float16 f16x8 __attribute__((ext_vector_type(8)));
typedef _Float16 f16x4 __attribute__((ext_vector_type(4)));
typedef float    f32x4 __attribute__((ext_vector_type(4)));

// ---------------- K1: projection GEMM (unchanged, validated) ----------------
__global__ __launch_bounds__(256) void k_proj(const float* __restrict__ Hs,
                                              const float* __restrict__ W,
                                              float* __restrict__ qkv) {
  __shared__ float As[16][68];
  __shared__ float Bs[16][68];
  const int bx = blockIdx.x, by = blockIdx.y;
  const int tid = threadIdx.x;
  const int ri = tid >> 4, ci = tid & 15;
  const int o0 = bx * 64, m0 = by * 64;
  float acc[4][4] = {};
  for (int k0 = 0; k0 < 512; k0 += 16) {
    __syncthreads();
    {
      const int m = tid >> 2, kq = (tid & 3) * 4;
      float4 va = *(const float4*)&Hs[(m0 + m) * 512 + k0 + kq];
      As[kq + 0][m] = va.x; As[kq + 1][m] = va.y; As[kq + 2][m] = va.z; As[kq + 3][m] = va.w;
      float4 vb = *(const float4*)&W[(o0 + m) * 512 + k0 + kq];
      Bs[kq + 0][m] = vb.x; Bs[kq + 1][m] = vb.y; Bs[kq + 2][m] = vb.z; Bs[kq + 3][m] = vb.w;
    }
    __syncthreads();
#pragma unroll
    for (int kk = 0; kk < 16; ++kk) {
      float4 a = *(const float4*)&As[kk][ri * 4];
      float4 b = *(const float4*)&Bs[kk][ci * 4];
      acc[0][0] += a.x * b.x; acc[0][1] += a.x * b.y; acc[0][2] += a.x * b.z; acc[0][3] += a.x * b.w;
      acc[1][0] += a.y * b.x; acc[1][1] += a.y * b.y; acc[1][2] += a.y * b.z; acc[1][3] += a.y * b.w;
      acc[2][0] += a.z * b.x; acc[2][1] += a.z * b.y; acc[2][2] += a.z * b.z; acc[2][3] += a.z * b.w;
      acc[3][0] += a.w * b.x; acc[3][1] += a.w * b.y; acc[3][2] += a.w * b.z; acc[3][3] += a.w * b.w;
    }
  }
  const int p = o0 >> 9;
  const int h = (o0 >> 6) & 7;
  const int d0 = ci * 4;
#pragma unroll
  for (int l = 0; l < 4; ++l) {
    const int r = m0 + ri * 4 + l;
    const int b = r >> 8, n = r & 255;
    float* dst = qkv + p * REG + (b * 8 + h) * (NN * DD) + n * DD + d0;
    *(float4*)dst = make_float4(acc[l][0], acc[l][1], acc[l][2], acc[l][3]);
  }
}

// ---------------- K2: score matrices (unchanged, validated) ----------------
__global__ __launch_bounds__(256) void k_scores(const float* __restrict__ qkv,
                                                float* __restrict__ ws) {
  __shared__ float Us[32][68];
  __shared__ float Ws_[32][68];
  const int ms = blockIdx.z, bh = blockIdx.y;
  const int tr = blockIdx.x >> 3, tc = blockIdx.x & 7;
  const float* U; const float* Wm; float* O;
  if (ms == 0)      { U = qkv + 0 * REG; Wm = qkv + 1 * REG; O = ws + OFF_X; }
  else if (ms == 1) { U = qkv + 1 * REG; Wm = qkv + 2 * REG; O = ws + OFF_Y; }
  else              { U = qkv + 2 * REG; Wm = qkv + 0 * REG; O = ws + OFF_Z; }
  U  += bh * (NN * DD);
  Wm += bh * (NN * DD);
  O  += bh * (NN * NN);
  const int i0 = tr * 32, k0 = tc * 32;
  const int tid = threadIdx.x;
  {
    const int r = tid >> 3, d8 = (tid & 7) * 8;
    *(float4*)&Us[r][d8]      = *(const float4*)&U[(i0 + r) * DD + d8];
    *(float4*)&Us[r][d8 + 4]  = *(const float4*)&U[(i0 + r) * DD + d8 + 4];
    *(float4*)&Ws_[r][d8]     = *(const float4*)&Wm[(k0 + r) * DD + d8];
    *(float4*)&Ws_[r][d8 + 4] = *(const float4*)&Wm[(k0 + r) * DD + d8 + 4];
  }
  __syncthreads();
  const int ri = tid >> 4, ci = tid & 15;
  float a00 = 0.f, a01 = 0.f, a10 = 0.f, a11 = 0.f;
#pragma unroll
  for (int dd = 0; dd < 16; ++dd) {
    float4 u0 = *(const float4*)&Us[ri][dd * 4];
    float4 u1 = *(const float4*)&Us[ri + 16][dd * 4];
    float4 w0 = *(const float4*)&Ws_[ci][dd * 4];
    float4 w1 = *(const float4*)&Ws_[ci + 16][dd * 4];
    a00 += u0.x * w0.x + u0.y * w0.y + u0.z * w0.z + u0.w * w0.w;
    a01 += u0.x * w1.x + u0.y * w1.y + u0.z * w1.z + u0.w * w1.w;
    a10 += u1.x * w0.x + u1.y * w0.y + u1.z * w0.z + u1.w * w0.w;
    a11 += u1.x * w1.x + u1.y * w1.y + u1.z * w1.z + u1.w * w1.w;
  }
#define STORE_SC(accv, rr, cc) { \
    int row = (rr), col = (cc); \
    O[row * NN + col] = (accv) * SCALER + fminf((float)(col - row), 0.f); }
  STORE_SC(a00, i0 + ri,      k0 + ci)
  STORE_SC(a01, i0 + ri,      k0 + ci + 16)
  STORE_SC(a10, i0 + ri + 16, k0 + ci)
  STORE_SC(a11, i0 + ri + 16, k0 + ci + 16)
#undef STORE_SC
}

// ---------------- K3: all max reductions in one kernel ----------------
// blk 0..1023: X row-max -> mx[4096] | 1024..2047: Y row-max -> yrow[4096]
// 2048..2111: Z col-max -> mz[4096]
__global__ __launch_bounds__(256) void k_maxes(const float* __restrict__ ws,
                                               float* __restrict__ mx,
                                               float* __restrict__ yrow,
                                               float* __restrict__ mz) {
  const int blk = blockIdx.x, tid = threadIdx.x;
  if (blk < 2048) {
    const int wid = tid >> 6, lane = tid & 63;
    const float* base = ws + (blk < 1024 ? OFF_X : OFF_Y);
    float* out = (blk < 1024) ? mx : yrow;
    const int gr = (blk & 1023) * 4 + wid;
    float4 v = *(const float4*)&base[gr * 256 + lane * 4];
    float m = fmaxf(fmaxf(v.x, v.y), fmaxf(v.z, v.w));
#pragma unroll
    for (int off = 32; off; off >>= 1) m = fmaxf(m, __shfl_xor(m, off));
    if (lane == 0) out[gr] = m;
  } else {
    const int b2 = blk - 2048;            // 0..63
    const int bh = b2 >> 2, ic = b2 & 3;
    const int il = tid & 63, kp = tid >> 6;
    const int i = ic * 64 + il;
    const float* Zb = ws + OFF_Z;
    float m = -3.4e38f;
    for (int k = kp; k < 256; k += 4) m = fmaxf(m, Zb[bh * (NN * NN) + k * NN + i]);
    __shared__ float red[4][64];
    red[kp][il] = m;
    __syncthreads();
    if (kp == 0)
      mz[bh * NN + i] = fmaxf(fmaxf(red[0][il], red[1][il]), fmaxf(red[2][il], red[3][il]));
  }
}

// ---------------- K3b: reduce yrow (4096) -> my[16] ----------------
__global__ __launch_bounds__(256) void k_ymax2(const float* __restrict__ yrow, float* __restrict__ my) {
  const int bh = blockIdx.x, tid = threadIdx.x;
  float m = yrow[bh * 256 + tid];
#pragma unroll
  for (int off = 32; off; off >>= 1) m = fmaxf(m, __shfl_xor(m, off));
  __shared__ float red[4];
  if ((tid & 63) == 0) red[tid >> 6] = m;
  __syncthreads();
  if (tid == 0) my[bh] = fmaxf(fmaxf(red[0], red[1]), fmaxf(red[2], red[3]));
}

// ---------------- K4: fused exp + convert + transpose ----------------
// blk 0..255: X->Xh fp16 (exp, row-max)        | 256..511: Y->Yt fp16 (exp, global-max, transpose)
// 512..575: v1t fp16 transpose (no exp)        | 576..639: v2t fp32 transpose (no exp)
// 640..1663: Z in-place exp fp32 (col-max)
__global__ __launch_bounds__(256) void k_cvtexp(float* __restrict__ ws) {
  __shared__ float T[64][65];
  const int blk = blockIdx.x, tid = threadIdx.x;
  if (blk < 256) {
    const float* X = ws + OFF_X;
    _Float16* Xh = (_Float16*)(ws + OFF_XH);
    const int gt = blk * 256 + tid;
    const int base = gt * 16;
    const float s = ws[OFF_MX + (gt >> 4)];      // global row = base/256
#pragma unroll
    for (int q = 0; q < 4; ++q) {
      float4 v = *(const float4*)&X[base + q * 4];
      f16x4 o = {(_Float16)expf(v.x - s), (_Float16)expf(v.y - s),
                 (_Float16)expf(v.z - s), (_Float16)expf(v.w - s)};
      *(f16x4*)&Xh[base + q * 4] = o;
    }
  } else if (blk < 512) {
    const int b2 = blk - 256;
    const int bh = b2 >> 4, jt = (b2 >> 2) & 3, kt = b2 & 3;
    const float* Y = ws + OFF_Y + bh * 65536;
    _Float16* Yt = (_Float16*)(ws + OFF_YT) + bh * 65536;
    const float s = ws[OFF_MY + bh];
    const int j0 = jt * 64, k0 = kt * 64;
#pragma unroll 4
    for (int p = 0; p < 16; ++p) {
      const int idx = p * 256 + tid, r = idx >> 6, c = idx & 63;
      T[r][c] = Y[(j0 + r) * 256 + k0 + c];
    }
    __syncthreads();
#pragma unroll 4
    for (int p = 0; p < 16; ++p) {
      const int idx = p * 256 + tid, r = idx >> 6, c = idx & 63;
      Yt[(k0 + r) * 256 + j0 + c] = (_Float16)expf(T[c][r] - s);
    }
  } else if (blk < 576) {
    const int b2 = blk - 512;
    const int bh = b2 >> 2, jt = b2 & 3;
    const float* v1 = ws + OFF_QKV + 3 * REG + bh * 16384;
    _Float16* v1t = (_Float16*)(ws + OFF_V1T) + bh * 16384;
    const int j0 = jt * 64;
#pragma unroll 4
    for (int p = 0; p < 16; ++p) {
      const int idx = p * 256 + tid, r = idx >> 6, c = idx & 63;
      T[r][c] = v1[(j0 + r) * 64 + c];
    }
    __syncthreads();
#pragma unroll 4
    for (int p = 0; p < 16; ++p) {
      const int idx = p * 256 + tid, r = idx >> 6, c = idx & 63;   // r=d, c=j-local
      v1t[r * 256 + j0 + c] = (_Float16)T[c][r];
    }
  } else if (blk < 640) {
    const int b2 = blk - 576;
    const int bh = b2 >> 2, kt = b2 & 3;
    const float* v2 = ws + OFF_QKV + 4 * REG + bh * 16384;
    float* v2t = ws + OFF_V2T + bh * 16384;
    const int k0 = kt * 64;
#pragma unroll 4
    for (int p = 0; p < 16; ++p) {
      const int idx = p * 256 + tid, r = idx >> 6, c = idx & 63;
      T[r][c] = v2[(k0 + r) * 64 + c];
    }
    __syncthreads();
#pragma unroll 4
    for (int p = 0; p < 16; ++p) {
      const int idx = p * 256 + tid, r = idx >> 6, c = idx & 63;   // r=d, c=k-local
      v2t[r * 256 + k0 + c] = T[c][r];
    }
  } else {
    const int rem = (blk - 640) * 256 + tid;       // float4 id in Z, 262144 total
    const int bh = rem >> 14, rr = rem & 16383;
    const int c4 = (rr & 63) * 4;
    float4* base = (float4*)(ws + OFF_Z);
    float4 v = base[rem];
    float4 s = *(const float4*)&ws[OFF_MZ + bh * NN + c4];
    v.x = expf(v.x - s.x); v.y = expf(v.y - s.y); v.z = expf(v.z - s.z); v.w = expf(v.w - s.w);
    base[rem] = v;
  }
}

// ---------------- K5: MFMA triple contraction, d-split 4-way ----------------
// grid (kb=4, ib=4, bh*4+dp=64).  Block handles d-slots [dp*16, dp*16+16);
// dp==3 additionally computes the down slot (v1=1, v2=1).
// Per-(k16,ir,it) result written exactly once -> plain LDS stores (no atomics),
// k16 partials summed at writeout.
__global__ __launch_bounds__(512) void k_heavy(const float* __restrict__ ws,
                                               float* __restrict__ upP,
                                               float* __restrict__ dnP) {
  const int kb = blockIdx.x, ib = blockIdx.y, zz = blockIdx.z;
  const int bh = zz >> 2, dp = zz & 3;
  const int k0 = kb * 64, i0 = ib * 64, d0 = dp * 16;
  const int tid = threadIdx.x;
  const int w = tid >> 6, lane = tid & 63;
  const int k16 = w & 3, ihalf = w >> 2;
  const int li = lane & 15, grp = lane >> 4;

  __shared__ _Float16 v1s[16 * 256];   // 8 KB
  __shared__ float v2s[16 * 64];       // 4 KB
  __shared__ float up_l[4][64][20];    // 20.5 KB (pad 20: 2-way bank alias = free)
  __shared__ float dn_l[4][64];        // 1 KB

  const _Float16* Xh  = (const _Float16*)(ws + OFF_XH);
  const _Float16* Yt  = (const _Float16*)(ws + OFF_YT);
  const _Float16* v1t = (const _Float16*)(ws + OFF_V1T);
  const float*    v2t = ws + OFF_V2T;
  const float*    Zp  = ws + OFF_Z + bh * 65536;

  // stage this block's 16 d-slots of v1t (8 KB) and v2t[:, k0:k0+64] (4 KB)
  {
    const float4* src = (const float4*)(v1t + bh * 16384 + d0 * 256);  // 512 float4
    ((float4*)v1s)[tid] = src[tid];
  }
  if (tid < 256) {
    const int d = tid >> 4, kq = (tid & 15) * 4;
    *(float4*)&v2s[d * 64 + kq] = *(const float4*)&v2t[bh * 16384 + (d0 + d) * 256 + k0 + kq];
  }

  // hoist fragments (d-independent) into registers
  f16x8 Yf[8];
  {
    const _Float16* yb = Yt + (long)bh * 65536 + (k0 + k16 * 16 + li) * 256 + grp * 8;
#pragma unroll
    for (int js = 0; js < 8; ++js) Yf[js] = *(const f16x8*)(yb + js * 32);
  }
  f16x8 Xf0[8], Xf1[8];
  {
    const _Float16* xb0 = Xh + (long)bh * 65536 + (i0 + (ihalf * 2 + 0) * 16 + li) * 256 + grp * 8;
    const _Float16* xb1 = Xh + (long)bh * 65536 + (i0 + (ihalf * 2 + 1) * 16 + li) * 256 + grp * 8;
#pragma unroll
    for (int js = 0; js < 8; ++js) { Xf0[js] = *(const f16x8*)(xb0 + js * 32); Xf1[js] = *(const f16x8*)(xb1 + js * 32); }
  }
  float Zr0[4], Zr1[4];
#pragma unroll
  for (int r = 0; r < 4; ++r) {
    const int kk = (k0 + k16 * 16 + grp * 4 + r) * 256 + i0;
    Zr0[r] = Zp[kk + (ihalf * 2 + 0) * 16 + li];
    Zr1[r] = Zp[kk + (ihalf * 2 + 1) * 16 + li];
  }

  __syncthreads();

  const int ir0 = (ihalf * 2 + 0) * 16 + li;
  const int ir1 = (ihalf * 2 + 1) * 16 + li;

  for (int it = 0; it < 16; ++it) {
    f32x4 acc0 = {0.f, 0.f, 0.f, 0.f}, acc1 = {0.f, 0.f, 0.f, 0.f};
#pragma unroll
    for (int js = 0; js < 8; ++js) {
      f16x8 vf = *(const f16x8*)&v1s[it * 256 + js * 32 + grp * 8];
      f16x8 ad = Yf[js] * vf;                         // A_d = Y ∘ v1_d
      acc0 = __builtin_amdgcn_mfma_f32_16x16x32_f16(ad, Xf0[js], acc0, 0, 0, 0);
      acc1 = __builtin_amdgcn_mfma_f32_16x16x32_f16(ad, Xf1[js], acc1, 0, 0, 0);
    }
    f32x4 w2 = *(const f32x4*)&v2s[it * 64 + k16 * 16 + grp * 4];
    float s0 = (acc0[0] * Zr0[0]) * w2[0] + (acc0[1] * Zr0[1]) * w2[1]
             + (acc0[2] * Zr0[2]) * w2[2] + (acc0[3] * Zr0[3]) * w2[3];
    float s1 = (acc1[0] * Zr1[0]) * w2[0] + (acc1[1] * Zr1[1]) * w2[1]
             + (acc1[2] * Zr1[2]) * w2[2] + (acc1[3] * Zr1[3]) * w2[3];
    s0 += __shfl_xor(s0, 16); s0 += __shfl_xor(s0, 32);
    s1 += __shfl_xor(s1, 16); s1 += __shfl_xor(s1, 32);
    if (lane < 16) {
      up_l[k16][ir0][it] = s0;
      up_l[k16][ir1][it] = s1;
    }
  }
  if (dp == 3) { // down slot: A = Y (v1 == 1), v2 == 1
    f32x4 acc0 = {0.f, 0.f, 0.f, 0.f}, acc1 = {0.f, 0.f, 0.f, 0.f};
#pragma unroll
    for (int js = 0; js < 8; ++js) {
      acc0 = __builtin_amdgcn_mfma_f32_16x16x32_f16(Yf[js], Xf0[js], acc0, 0, 0, 0);
      acc1 = __builtin_amdgcn_mfma_f32_16x16x32_f16(Yf[js], Xf1[js], acc1, 0, 0, 0);
    }
    float s0 = acc0[0] * Zr0[0] + acc0[1] * Zr0[1] + acc0[2] * Zr0[2] + acc0[3] * Zr0[3];
    float s1 = acc1[0] * Zr1[0] + acc1[1] * Zr1[1] + acc1[2] * Zr1[2] + acc1[3] * Zr1[3];
    s0 += __shfl_xor(s0, 16); s0 += __shfl_xor(s0, 32);
    s1 += __shfl_xor(s1, 16); s1 += __shfl_xor(s1, 32);
    if (lane < 16) {
      dn_l[k16][ir0] = s0;
      dn_l[k16][ir1] = s1;
    }
  }
  __syncthreads();
  // writeout: sum the 4 k16 partials
  {
    const int il = tid >> 3, dq = (tid & 7) * 2;
    float a = up_l[0][il][dq]     + up_l[1][il][dq]     + up_l[2][il][dq]     + up_l[3][il][dq];
    float b = up_l[0][il][dq + 1] + up_l[1][il][dq + 1] + up_l[2][il][dq + 1] + up_l[3][il][dq + 1];
    float* dst = upP + ((long)((kb * 16 + bh) * 256) + i0 + il) * 64 + d0 + dq;
    dst[0] = a; dst[1] = b;
  }
  if (dp == 3 && tid < 64)
    dnP[(kb * 16 + bh) * 256 + i0 + tid] =
        dn_l[0][tid] + dn_l[1][tid] + dn_l[2][tid] + dn_l[3][tid];
}

// ---------------- K6: combine 4 k-partials, divide, write [b][n][h*64+d] ----------------
__global__ __launch_bounds__(256) void k_final(const float* __restrict__ ws_in, float* __restrict__ out) {
  const int g = blockIdx.x * 256 + threadIdx.x;  // float4 id, 65536 total
  const int e0 = g * 4;
  const int c = e0 & 511, n = (e0 >> 9) & 255, b = e0 >> 17;
  const int h = c >> 6, d = c & 63;
  const int bh = b * 8 + h;
  const float* upP = ws_in + OFF_UP;
  const float* dnP = ws_in + OFF_DN;
  float4 acc = make_float4(0.f, 0.f, 0.f, 0.f);
  float dn = 0.f;
#pragma unroll
  for (int ks = 0; ks < KB; ++ks) {
    const float4 u = *(const float4*)&upP[((ks * 16 + bh) * 256 + n) * 64 + d];
    acc.x += u.x; acc.y += u.y; acc.z += u.z; acc.w += u.w;
    dn += dnP[(ks * 16 + bh) * 256 + n];
  }
  const float inv = 1.f / (dn + 1e-9f);
  acc.x *= inv; acc.y *= inv; acc.z *= inv; acc.w *= inv;
  *(float4*)&out[e0] = acc;
}

extern "C" void kernel_launch(void* const* d_in, const int* in_sizes, int n_in,
                              void* d_out, int out_size, void* d_ws, size_t ws_size,
                              hipStream_t stream) {
  (void)in_sizes; (void)n_in; (void)out_size; (void)ws_size;
  const float* hidden = (const float*)d_in[0];
  const float* W      = (const float*)d_in[1];
  float* ws  = (float*)d_ws;
  float* out = (float*)d_out;

  k_proj<<<dim3(40, 8), 256, 0, stream>>>(hidden, W, ws + OFF_QKV);
  k_scores<<<dim3(64, BH, 3), 256, 0, stream>>>(ws + OFF_QKV, ws);
  k_maxes<<<dim3(2112), 256, 0, stream>>>(ws, ws + OFF_MX, ws + OFF_YR, ws + OFF_MZ);
  k_ymax2<<<dim3(16), 256, 0, stream>>>(ws + OFF_YR, ws + OFF_MY);
  k_cvtexp<<<dim3(1664), 256, 0, stream>>>(ws);
  k_heavy<<<dim3(KB, 4, 64), 512, 0, stream>>>(ws, ws + OFF_UP, ws + OFF_DN);
  k_final<<<dim3(256), 256, 0, stream>>>(ws, out);
}

// Round 7
// 185.103 us; speedup vs baseline: 3.8441x; 1.0340x over previous
//
#include <hip/hip_runtime.h>
#include <math.h>

#define NN 256
#define HH 8
#define DD 64
#define BH 16
#define SCALER 0.125f

#define REG     (BH*NN*DD)             // 262144 floats
#define MAT_SZ  (BH*NN*NN)             // 1048576 floats
// fp16 buffers overlay the dead a/b/c projections (only v1,v2 at 3*REG,4*REG live on)
#define OFF_XH  0                      // fp16 [bh][i][j]
#define OFF_V1T 524288                 // fp16 [bh][d][j]
#define OFF_QKV 0
#define OFF_X   1310720
#define OFF_Y   (OFF_X + MAT_SZ)
#define OFF_Z   (OFF_Y + MAT_SZ)
#define OFF_MX  (OFF_Z + MAT_SZ)       // 4096
#define OFF_MY  (OFF_MX + BH*NN)       // 16
#define OFF_MZ  (OFF_MY + 16)          // 4096
#define OFF_YT  4464656                // fp16 [bh][k][j]
#define OFF_V2T 4988944                // fp32 [bh][d][k]
#define KB      4
#define OFF_UP  5251088                // fp32 [kb][bh][i][d]
#define OFF_DN  6299664                // fp32 [kb][bh][i]  (16384)
#define OFF_YR  6316048                // fp32 yrow[4096]
// end 6320144 floats = 25.3 MB

typedef _Float16 f16x8 __attribute__((ext_vector_type(8)));
typedef _Float16 f16x4 __attribute__((ext_vector_type(4)));
typedef float    f32x4 __attribute__((ext_vector_type(4)));

// ---------------- K1: projection GEMM (unchanged, validated) ----------------
__global__ __launch_bounds__(256) void k_proj(const float* __restrict__ Hs,
                                              const float* __restrict__ W,
                                              float* __restrict__ qkv) {
  __shared__ float As[16][68];
  __shared__ float Bs[16][68];
  const int bx = blockIdx.x, by = blockIdx.y;
  const int tid = threadIdx.x;
  const int ri = tid >> 4, ci = tid & 15;
  const int o0 = bx * 64, m0 = by * 64;
  float acc[4][4] = {};
  for (int k0 = 0; k0 < 512; k0 += 16) {
    __syncthreads();
    {
      const int m = tid >> 2, kq = (tid & 3) * 4;
      float4 va = *(const float4*)&Hs[(m0 + m) * 512 + k0 + kq];
      As[kq + 0][m] = va.x; As[kq + 1][m] = va.y; As[kq + 2][m] = va.z; As[kq + 3][m] = va.w;
      float4 vb = *(const float4*)&W[(o0 + m) * 512 + k0 + kq];
      Bs[kq + 0][m] = vb.x; Bs[kq + 1][m] = vb.y; Bs[kq + 2][m] = vb.z; Bs[kq + 3][m] = vb.w;
    }
    __syncthreads();
#pragma unroll
    for (int kk = 0; kk < 16; ++kk) {
      float4 a = *(const float4*)&As[kk][ri * 4];
      float4 b = *(const float4*)&Bs[kk][ci * 4];
      acc[0][0] += a.x * b.x; acc[0][1] += a.x * b.y; acc[0][2] += a.x * b.z; acc[0][3] += a.x * b.w;
      acc[1][0] += a.y * b.x; acc[1][1] += a.y * b.y; acc[1][2] += a.y * b.z; acc[1][3] += a.y * b.w;
      acc[2][0] += a.z * b.x; acc[2][1] += a.z * b.y; acc[2][2] += a.z * b.z; acc[2][3] += a.z * b.w;
      acc[3][0] += a.w * b.x; acc[3][1] += a.w * b.y; acc[3][2] += a.w * b.z; acc[3][3] += a.w * b.w;
    }
  }
  const int p = o0 >> 9;
  const int h = (o0 >> 6) & 7;
  const int d0 = ci * 4;
#pragma unroll
  for (int l = 0; l < 4; ++l) {
    const int r = m0 + ri * 4 + l;
    const int b = r >> 8, n = r & 255;
    float* dst = qkv + p * REG + (b * 8 + h) * (NN * DD) + n * DD + d0;
    *(float4*)dst = make_float4(acc[l][0], acc[l][1], acc[l][2], acc[l][3]);
  }
}

// ---------------- K2: score matrices (unchanged, validated) ----------------
__global__ __launch_bounds__(256) void k_scores(const float* __restrict__ qkv,
                                                float* __restrict__ ws) {
  __shared__ float Us[32][68];
  __shared__ float Ws_[32][68];
  const int ms = blockIdx.z, bh = blockIdx.y;
  const int tr = blockIdx.x >> 3, tc = blockIdx.x & 7;
  const float* U; const float* Wm; float* O;
  if (ms == 0)      { U = qkv + 0 * REG; Wm = qkv + 1 * REG; O = ws + OFF_X; }
  else if (ms == 1) { U = qkv + 1 * REG; Wm = qkv + 2 * REG; O = ws + OFF_Y; }
  else              { U = qkv + 2 * REG; Wm = qkv + 0 * REG; O = ws + OFF_Z; }
  U  += bh * (NN * DD);
  Wm += bh * (NN * DD);
  O  += bh * (NN * NN);
  const int i0 = tr * 32, k0 = tc * 32;
  const int tid = threadIdx.x;
  {
    const int r = tid >> 3, d8 = (tid & 7) * 8;
    *(float4*)&Us[r][d8]      = *(const float4*)&U[(i0 + r) * DD + d8];
    *(float4*)&Us[r][d8 + 4]  = *(const float4*)&U[(i0 + r) * DD + d8 + 4];
    *(float4*)&Ws_[r][d8]     = *(const float4*)&Wm[(k0 + r) * DD + d8];
    *(float4*)&Ws_[r][d8 + 4] = *(const float4*)&Wm[(k0 + r) * DD + d8 + 4];
  }
  __syncthreads();
  const int ri = tid >> 4, ci = tid & 15;
  float a00 = 0.f, a01 = 0.f, a10 = 0.f, a11 = 0.f;
#pragma unroll
  for (int dd = 0; dd < 16; ++dd) {
    float4 u0 = *(const float4*)&Us[ri][dd * 4];
    float4 u1 = *(const float4*)&Us[ri + 16][dd * 4];
    float4 w0 = *(const float4*)&Ws_[ci][dd * 4];
    float4 w1 = *(const float4*)&Ws_[ci + 16][dd * 4];
    a00 += u0.x * w0.x + u0.y * w0.y + u0.z * w0.z + u0.w * w0.w;
    a01 += u0.x * w1.x + u0.y * w1.y + u0.z * w1.z + u0.w * w1.w;
    a10 += u1.x * w0.x + u1.y * w0.y + u1.z * w0.z + u1.w * w0.w;
    a11 += u1.x * w1.x + u1.y * w1.y + u1.z * w1.z + u1.w * w1.w;
  }
#define STORE_SC(accv, rr, cc) { \
    int row = (rr), col = (cc); \
    O[row * NN + col] = (accv) * SCALER + fminf((float)(col - row), 0.f); }
  STORE_SC(a00, i0 + ri,      k0 + ci)
  STORE_SC(a01, i0 + ri,      k0 + ci + 16)
  STORE_SC(a10, i0 + ri + 16, k0 + ci)
  STORE_SC(a11, i0 + ri + 16, k0 + ci + 16)
#undef STORE_SC
}

// ---------------- K3: all max reductions in one kernel ----------------
__global__ __launch_bounds__(256) void k_maxes(const float* __restrict__ ws,
                                               float* __restrict__ mx,
                                               float* __restrict__ yrow,
                                               float* __restrict__ mz) {
  const int blk = blockIdx.x, tid = threadIdx.x;
  if (blk < 2048) {
    const int wid = tid >> 6, lane = tid & 63;
    const float* base = ws + (blk < 1024 ? OFF_X : OFF_Y);
    float* out = (blk < 1024) ? mx : yrow;
    const int gr = (blk & 1023) * 4 + wid;
    float4 v = *(const float4*)&base[gr * 256 + lane * 4];
    float m = fmaxf(fmaxf(v.x, v.y), fmaxf(v.z, v.w));
#pragma unroll
    for (int off = 32; off; off >>= 1) m = fmaxf(m, __shfl_xor(m, off));
    if (lane == 0) out[gr] = m;
  } else {
    const int b2 = blk - 2048;            // 0..63
    const int bh = b2 >> 2, ic = b2 & 3;
    const int il = tid & 63, kp = tid >> 6;
    const int i = ic * 64 + il;
    const float* Zb = ws + OFF_Z;
    float m = -3.4e38f;
    for (int k = kp; k < 256; k += 4) m = fmaxf(m, Zb[bh * (NN * NN) + k * NN + i]);
    __shared__ float red[4][64];
    red[kp][il] = m;
    __syncthreads();
    if (kp == 0)
      mz[bh * NN + i] = fmaxf(fmaxf(red[0][il], red[1][il]), fmaxf(red[2][il], red[3][il]));
  }
}

// ---------------- K3b: reduce yrow (4096) -> my[16] ----------------
__global__ __launch_bounds__(256) void k_ymax2(const float* __restrict__ yrow, float* __restrict__ my) {
  const int bh = blockIdx.x, tid = threadIdx.x;
  float m = yrow[bh * 256 + tid];
#pragma unroll
  for (int off = 32; off; off >>= 1) m = fmaxf(m, __shfl_xor(m, off));
  __shared__ float red[4];
  if ((tid & 63) == 0) red[tid >> 6] = m;
  __syncthreads();
  if (tid == 0) my[bh] = fmaxf(fmaxf(red[0], red[1]), fmaxf(red[2], red[3]));
}

// ---------------- K4: fused exp + convert + transpose (unchanged) ----------------
__global__ __launch_bounds__(256) void k_cvtexp(float* __restrict__ ws) {
  __shared__ float T[64][65];
  const int blk = blockIdx.x, tid = threadIdx.x;
  if (blk < 256) {
    const float* X = ws + OFF_X;
    _Float16* Xh = (_Float16*)(ws + OFF_XH);
    const int gt = blk * 256 + tid;
    const int base = gt * 16;
    const float s = ws[OFF_MX + (gt >> 4)];
#pragma unroll
    for (int q = 0; q < 4; ++q) {
      float4 v = *(const float4*)&X[base + q * 4];
      f16x4 o = {(_Float16)expf(v.x - s), (_Float16)expf(v.y - s),
                 (_Float16)expf(v.z - s), (_Float16)expf(v.w - s)};
      *(f16x4*)&Xh[base + q * 4] = o;
    }
  } else if (blk < 512) {
    const int b2 = blk - 256;
    const int bh = b2 >> 4, jt = (b2 >> 2) & 3, kt = b2 & 3;
    const float* Y = ws + OFF_Y + bh * 65536;
    _Float16* Yt = (_Float16*)(ws + OFF_YT) + bh * 65536;
    const float s = ws[OFF_MY + bh];
    const int j0 = jt * 64, k0 = kt * 64;
#pragma unroll 4
    for (int p = 0; p < 16; ++p) {
      const int idx = p * 256 + tid, r = idx >> 6, c = idx & 63;
      T[r][c] = Y[(j0 + r) * 256 + k0 + c];
    }
    __syncthreads();
#pragma unroll 4
    for (int p = 0; p < 16; ++p) {
      const int idx = p * 256 + tid, r = idx >> 6, c = idx & 63;
      Yt[(k0 + r) * 256 + j0 + c] = (_Float16)expf(T[c][r] - s);
    }
  } else if (blk < 576) {
    const int b2 = blk - 512;
    const int bh = b2 >> 2, jt = b2 & 3;
    const float* v1 = ws + OFF_QKV + 3 * REG + bh * 16384;
    _Float16* v1t = (_Float16*)(ws + OFF_V1T) + bh * 16384;
    const int j0 = jt * 64;
#pragma unroll 4
    for (int p = 0; p < 16; ++p) {
      const int idx = p * 256 + tid, r = idx >> 6, c = idx & 63;
      T[r][c] = v1[(j0 + r) * 64 + c];
    }
    __syncthreads();
#pragma unroll 4
    for (int p = 0; p < 16; ++p) {
      const int idx = p * 256 + tid, r = idx >> 6, c = idx & 63;
      v1t[r * 256 + j0 + c] = (_Float16)T[c][r];
    }
  } else if (blk < 640) {
    const int b2 = blk - 576;
    const int bh = b2 >> 2, kt = b2 & 3;
    const float* v2 = ws + OFF_QKV + 4 * REG + bh * 16384;
    float* v2t = ws + OFF_V2T + bh * 16384;
    const int k0 = kt * 64;
#pragma unroll 4
    for (int p = 0; p < 16; ++p) {
      const int idx = p * 256 + tid, r = idx >> 6, c = idx & 63;
      T[r][c] = v2[(k0 + r) * 64 + c];
    }
    __syncthreads();
#pragma unroll 4
    for (int p = 0; p < 16; ++p) {
      const int idx = p * 256 + tid, r = idx >> 6, c = idx & 63;
      v2t[r * 256 + k0 + c] = T[c][r];
    }
  } else {
    const int rem = (blk - 640) * 256 + tid;
    const int bh = rem >> 14, rr = rem & 16383;
    const int c4 = (rr & 63) * 4;
    float4* base = (float4*)(ws + OFF_Z);
    float4 v = base[rem];
    float4 s = *(const float4*)&ws[OFF_MZ + bh * NN + c4];
    v.x = expf(v.x - s.x); v.y = expf(v.y - s.y); v.z = expf(v.z - s.z); v.w = expf(v.w - s.w);
    base[rem] = v;
  }
}

// ---------------- K5: MFMA triple contraction, d-split + 8-stream ILP ----------------
// v3: batch 2 d-slots per iteration, split each 8-js chain into two 4-js halves:
// 8 independent MFMA accumulation streams (was 2) to break the dependent-MFMA
// latency chain that made rounds 5/6 invariant at ~62 us.
__global__ __launch_bounds__(512) void k_heavy(const float* __restrict__ ws,
                                               float* __restrict__ upP,
                                               float* __restrict__ dnP) {
  const int kb = blockIdx.x, ib = blockIdx.y, zz = blockIdx.z;
  const int bh = zz >> 2, dp = zz & 3;
  const int k0 = kb * 64, i0 = ib * 64, d0 = dp * 16;
  const int tid = threadIdx.x;
  const int w = tid >> 6, lane = tid & 63;
  const int k16 = w & 3, ihalf = w >> 2;
  const int li = lane & 15, grp = lane >> 4;

  __shared__ _Float16 v1s[16 * 256];   // 8 KB
  __shared__ float v2s[16 * 64];       // 4 KB
  __shared__ float up_l[4][64][20];    // 20.5 KB
  __shared__ float dn_l[4][64];        // 1 KB

  const _Float16* Xh  = (const _Float16*)(ws + OFF_XH);
  const _Float16* Yt  = (const _Float16*)(ws + OFF_YT);
  const _Float16* v1t = (const _Float16*)(ws + OFF_V1T);
  const float*    v2t = ws + OFF_V2T;
  const float*    Zp  = ws + OFF_Z + bh * 65536;

  {
    const float4* src = (const float4*)(v1t + bh * 16384 + d0 * 256);
    ((float4*)v1s)[tid] = src[tid];
  }
  if (tid < 256) {
    const int d = tid >> 4, kq = (tid & 15) * 4;
    *(float4*)&v2s[d * 64 + kq] = *(const float4*)&v2t[bh * 16384 + (d0 + d) * 256 + k0 + kq];
  }

  f16x8 Yf[8];
  {
    const _Float16* yb = Yt + (long)bh * 65536 + (k0 + k16 * 16 + li) * 256 + grp * 8;
#pragma unroll
    for (int js = 0; js < 8; ++js) Yf[js] = *(const f16x8*)(yb + js * 32);
  }
  f16x8 Xf0[8], Xf1[8];
  {
    const _Float16* xb0 = Xh + (long)bh * 65536 + (i0 + (ihalf * 2 + 0) * 16 + li) * 256 + grp * 8;
    const _Float16* xb1 = Xh + (long)bh * 65536 + (i0 + (ihalf * 2 + 1) * 16 + li) * 256 + grp * 8;
#pragma unroll
    for (int js = 0; js < 8; ++js) { Xf0[js] = *(const f16x8*)(xb0 + js * 32); Xf1[js] = *(const f16x8*)(xb1 + js * 32); }
  }
  float Zr0[4], Zr1[4];
#pragma unroll
  for (int r = 0; r < 4; ++r) {
    const int kk = (k0 + k16 * 16 + grp * 4 + r) * 256 + i0;
    Zr0[r] = Zp[kk + (ihalf * 2 + 0) * 16 + li];
    Zr1[r] = Zp[kk + (ihalf * 2 + 1) * 16 + li];
  }

  __syncthreads();

  const int ir0 = (ihalf * 2 + 0) * 16 + li;
  const int ir1 = (ihalf * 2 + 1) * 16 + li;

  for (int it = 0; it < 16; it += 2) {
    // 8 independent accumulation streams: {d=it, d=it+1} x {i-half0, i-half1} x {js 0-3, js 4-7}
    f32x4 aA0 = {0.f,0.f,0.f,0.f}, aA1 = {0.f,0.f,0.f,0.f};  // d=it,   js0-3
    f32x4 aB0 = {0.f,0.f,0.f,0.f}, aB1 = {0.f,0.f,0.f,0.f};  // d=it,   js4-7
    f32x4 cA0 = {0.f,0.f,0.f,0.f}, cA1 = {0.f,0.f,0.f,0.f};  // d=it+1, js0-3
    f32x4 cB0 = {0.f,0.f,0.f,0.f}, cB1 = {0.f,0.f,0.f,0.f};  // d=it+1, js4-7
#pragma unroll
    for (int js = 0; js < 4; ++js) {
      f16x8 vf0 = *(const f16x8*)&v1s[it * 256 + js * 32 + grp * 8];
      f16x8 vf1 = *(const f16x8*)&v1s[(it + 1) * 256 + js * 32 + grp * 8];
      f16x8 ad0 = Yf[js] * vf0;
      f16x8 ad1 = Yf[js] * vf1;
      aA0 = __builtin_amdgcn_mfma_f32_16x16x32_f16(ad0, Xf0[js], aA0, 0, 0, 0);
      aA1 = __builtin_amdgcn_mfma_f32_16x16x32_f16(ad0, Xf1[js], aA1, 0, 0, 0);
      cA0 = __builtin_amdgcn_mfma_f32_16x16x32_f16(ad1, Xf0[js], cA0, 0, 0, 0);
      cA1 = __builtin_amdgcn_mfma_f32_16x16x32_f16(ad1, Xf1[js], cA1, 0, 0, 0);
    }
#pragma unroll
    for (int js = 4; js < 8; ++js) {
      f16x8 vf0 = *(const f16x8*)&v1s[it * 256 + js * 32 + grp * 8];
      f16x8 vf1 = *(const f16x8*)&v1s[(it + 1) * 256 + js * 32 + grp * 8];
      f16x8 ad0 = Yf[js] * vf0;
      f16x8 ad1 = Yf[js] * vf1;
      aB0 = __builtin_amdgcn_mfma_f32_16x16x32_f16(ad0, Xf0[js], aB0, 0, 0, 0);
      aB1 = __builtin_amdgcn_mfma_f32_16x16x32_f16(ad0, Xf1[js], aB1, 0, 0, 0);
      cB0 = __builtin_amdgcn_mfma_f32_16x16x32_f16(ad1, Xf0[js], cB0, 0, 0, 0);
      cB1 = __builtin_amdgcn_mfma_f32_16x16x32_f16(ad1, Xf1[js], cB1, 0, 0, 0);
    }
    f32x4 acc0 = aA0 + aB0, acc1 = aA1 + aB1;   // d=it
    f32x4 dcc0 = cA0 + cB0, dcc1 = cA1 + cB1;   // d=it+1
    {
      f32x4 w2 = *(const f32x4*)&v2s[it * 64 + k16 * 16 + grp * 4];
      float s0 = (acc0[0] * Zr0[0]) * w2[0] + (acc0[1] * Zr0[1]) * w2[1]
               + (acc0[2] * Zr0[2]) * w2[2] + (acc0[3] * Zr0[3]) * w2[3];
      float s1 = (acc1[0] * Zr1[0]) * w2[0] + (acc1[1] * Zr1[1]) * w2[1]
               + (acc1[2] * Zr1[2]) * w2[2] + (acc1[3] * Zr1[3]) * w2[3];
      s0 += __shfl_xor(s0, 16); s0 += __shfl_xor(s0, 32);
      s1 += __shfl_xor(s1, 16); s1 += __shfl_xor(s1, 32);
      if (lane < 16) {
        up_l[k16][ir0][it] = s0;
        up_l[k16][ir1][it] = s1;
      }
    }
    {
      f32x4 w2 = *(const f32x4*)&v2s[(it + 1) * 64 + k16 * 16 + grp * 4];
      float s0 = (dcc0[0] * Zr0[0]) * w2[0] + (dcc0[1] * Zr0[1]) * w2[1]
               + (dcc0[2] * Zr0[2]) * w2[2] + (dcc0[3] * Zr0[3]) * w2[3];
      float s1 = (dcc1[0] * Zr1[0]) * w2[0] + (dcc1[1] * Zr1[1]) * w2[1]
               + (dcc1[2] * Zr1[2]) * w2[2] + (dcc1[3] * Zr1[3]) * w2[3];
      s0 += __shfl_xor(s0, 16); s0 += __shfl_xor(s0, 32);
      s1 += __shfl_xor(s1, 16); s1 += __shfl_xor(s1, 32);
      if (lane < 16) {
        up_l[k16][ir0][it + 1] = s0;
        up_l[k16][ir1][it + 1] = s1;
      }
    }
  }
  if (dp == 3) { // down slot: A = Y (v1 == 1), v2 == 1; 4 streams
    f32x4 aA0 = {0.f,0.f,0.f,0.f}, aA1 = {0.f,0.f,0.f,0.f};
    f32x4 aB0 = {0.f,0.f,0.f,0.f}, aB1 = {0.f,0.f,0.f,0.f};
#pragma unroll
    for (int js = 0; js < 4; ++js) {
      aA0 = __builtin_amdgcn_mfma_f32_16x16x32_f16(Yf[js], Xf0[js], aA0, 0, 0, 0);
      aA1 = __builtin_amdgcn_mfma_f32_16x16x32_f16(Yf[js], Xf1[js], aA1, 0, 0, 0);
      aB0 = __builtin_amdgcn_mfma_f32_16x16x32_f16(Yf[js + 4], Xf0[js + 4], aB0, 0, 0, 0);
      aB1 = __builtin_amdgcn_mfma_f32_16x16x32_f16(Yf[js + 4], Xf1[js + 4], aB1, 0, 0, 0);
    }
    f32x4 acc0 = aA0 + aB0, acc1 = aA1 + aB1;
    float s0 = acc0[0] * Zr0[0] + acc0[1] * Zr0[1] + acc0[2] * Zr0[2] + acc0[3] * Zr0[3];
    float s1 = acc1[0] * Zr1[0] + acc1[1] * Zr1[1] + acc1[2] * Zr1[2] + acc1[3] * Zr1[3];
    s0 += __shfl_xor(s0, 16); s0 += __shfl_xor(s0, 32);
    s1 += __shfl_xor(s1, 16); s1 += __shfl_xor(s1, 32);
    if (lane < 16) {
      dn_l[k16][ir0] = s0;
      dn_l[k16][ir1] = s1;
    }
  }
  __syncthreads();
  {
    const int il = tid >> 3, dq = (tid & 7) * 2;
    float a = up_l[0][il][dq]     + up_l[1][il][dq]     + up_l[2][il][dq]     + up_l[3][il][dq];
    float b = up_l[0][il][dq + 1] + up_l[1][il][dq + 1] + up_l[2][il][dq + 1] + up_l[3][il][dq + 1];
    float* dst = upP + ((long)((kb * 16 + bh) * 256) + i0 + il) * 64 + d0 + dq;
    dst[0] = a; dst[1] = b;
  }
  if (dp == 3 && tid < 64)
    dnP[(kb * 16 + bh) * 256 + i0 + tid] =
        dn_l[0][tid] + dn_l[1][tid] + dn_l[2][tid] + dn_l[3][tid];
}

// ---------------- K6: combine 4 k-partials, divide, write [b][n][h*64+d] ----------------
__global__ __launch_bounds__(256) void k_final(const float* __restrict__ ws_in, float* __restrict__ out) {
  const int g = blockIdx.x * 256 + threadIdx.x;
  const int e0 = g * 4;
  const int c = e0 & 511, n = (e0 >> 9) & 255, b = e0 >> 17;
  const int h = c >> 6, d = c & 63;
  const int bh = b * 8 + h;
  const float* upP = ws_in + OFF_UP;
  const float* dnP = ws_in + OFF_DN;
  float4 acc = make_float4(0.f, 0.f, 0.f, 0.f);
  float dn = 0.f;
#pragma unroll
  for (int ks = 0; ks < KB; ++ks) {
    const float4 u = *(const float4*)&upP[((ks * 16 + bh) * 256 + n) * 64 + d];
    acc.x += u.x; acc.y += u.y; acc.z += u.z; acc.w += u.w;
    dn += dnP[(ks * 16 + bh) * 256 + n];
  }
  const float inv = 1.f / (dn + 1e-9f);
  acc.x *= inv; acc.y *= inv; acc.z *= inv; acc.w *= inv;
  *(float4*)&out[e0] = acc;
}

extern "C" void kernel_launch(void* const* d_in, const int* in_sizes, int n_in,
                              void* d_out, int out_size, void* d_ws, size_t ws_size,
                              hipStream_t stream) {
  (void)in_sizes; (void)n_in; (void)out_size; (void)ws_size;
  const float* hidden = (const float*)d_in[0];
  const float* W      = (const float*)d_in[1];
  float* ws  = (float*)d_ws;
  float* out = (float*)d_out;

  k_proj<<<dim3(40, 8), 256, 0, stream>>>(hidden, W, ws + OFF_QKV);
  k_scores<<<dim3(64, BH, 3), 256, 0, stream>>>(ws + OFF_QKV, ws);
  k_maxes<<<dim3(2112), 256, 0, stream>>>(ws, ws + OFF_MX, ws + OFF_YR, ws + OFF_MZ);
  k_ymax2<<<dim3(16), 256, 0, stream>>>(ws + OFF_YR, ws + OFF_MY);
  k_cvtexp<<<dim3(1664), 256, 0, stream>>>(ws);
  k_heavy<<<dim3(KB, 4, 64), 512, 0, stream>>>(ws, ws + OFF_UP, ws + OFF_DN);
  k_final<<<dim3(256), 256, 0, stream>>>(ws, out);
}

// Round 12
// 184.577 us; speedup vs baseline: 3.8551x; 1.0028x over previous
//
#include <hip/hip_runtime.h>
#include <math.h>

#define NN 256
#define HH 8
#define DD 64
#define BH 16
#define SCALER 0.125f

#define REG     (BH*NN*DD)             // 262144 floats
#define MAT_SZ  (BH*NN*NN)             // 1048576 floats
// fp16 buffers overlay the dead a/b/c projections (only v1,v2 at 3*REG,4*REG live on)
#define OFF_XH  0                      // fp16 [bh][i][j]
#define OFF_V1T 524288                 // fp16 [bh][d][j]
#define OFF_QKV 0
#define OFF_X   1310720
#define OFF_Y   (OFF_X + MAT_SZ)
#define OFF_Z   (OFF_Y + MAT_SZ)
#define OFF_MX  (OFF_Z + MAT_SZ)       // 4096
#define OFF_MY  (OFF_MX + BH*NN)       // 16
#define OFF_MZ  (OFF_MY + 16)          // 4096
#define OFF_YT  4464656                // fp16 [bh][k][j]
#define OFF_V2T 4988944                // fp32 [bh][d][k]
#define KB      4
#define OFF_UP  5251088                // fp32 [kb][bh][i][d]
#define OFF_DN  6299664                // fp32 [kb][bh][i]  (16384)
#define OFF_YR  6316048                // fp32 yrow[4096]
// end 6320144 floats = 25.3 MB

typedef _Float16 f16x8 __attribute__((ext_vector_type(8)));
typedef _Float16 f16x4 __attribute__((ext_vector_type(4)));
typedef float    f32x4 __attribute__((ext_vector_type(4)));

// ---------------- K1: projection GEMM (unchanged, validated) ----------------
__global__ __launch_bounds__(256) void k_proj(const float* __restrict__ Hs,
                                              const float* __restrict__ W,
                                              float* __restrict__ qkv) {
  __shared__ float As[16][68];
  __shared__ float Bs[16][68];
  const int bx = blockIdx.x, by = blockIdx.y;
  const int tid = threadIdx.x;
  const int ri = tid >> 4, ci = tid & 15;
  const int o0 = bx * 64, m0 = by * 64;
  float acc[4][4] = {};
  for (int k0 = 0; k0 < 512; k0 += 16) {
    __syncthreads();
    {
      const int m = tid >> 2, kq = (tid & 3) * 4;
      float4 va = *(const float4*)&Hs[(m0 + m) * 512 + k0 + kq];
      As[kq + 0][m] = va.x; As[kq + 1][m] = va.y; As[kq + 2][m] = va.z; As[kq + 3][m] = va.w;
      float4 vb = *(const float4*)&W[(o0 + m) * 512 + k0 + kq];
      Bs[kq + 0][m] = vb.x; Bs[kq + 1][m] = vb.y; Bs[kq + 2][m] = vb.z; Bs[kq + 3][m] = vb.w;
    }
    __syncthreads();
#pragma unroll
    for (int kk = 0; kk < 16; ++kk) {
      float4 a = *(const float4*)&As[kk][ri * 4];
      float4 b = *(const float4*)&Bs[kk][ci * 4];
      acc[0][0] += a.x * b.x; acc[0][1] += a.x * b.y; acc[0][2] += a.x * b.z; acc[0][3] += a.x * b.w;
      acc[1][0] += a.y * b.x; acc[1][1] += a.y * b.y; acc[1][2] += a.y * b.z; acc[1][3] += a.y * b.w;
      acc[2][0] += a.z * b.x; acc[2][1] += a.z * b.y; acc[2][2] += a.z * b.z; acc[2][3] += a.z * b.w;
      acc[3][0] += a.w * b.x; acc[3][1] += a.w * b.y; acc[3][2] += a.w * b.z; acc[3][3] += a.w * b.w;
    }
  }
  const int p = o0 >> 9;
  const int h = (o0 >> 6) & 7;
  const int d0 = ci * 4;
#pragma unroll
  for (int l = 0; l < 4; ++l) {
    const int r = m0 + ri * 4 + l;
    const int b = r >> 8, n = r & 255;
    float* dst = qkv + p * REG + (b * 8 + h) * (NN * DD) + n * DD + d0;
    *(float4*)dst = make_float4(acc[l][0], acc[l][1], acc[l][2], acc[l][3]);
  }
}

// ---------------- K2: score matrices (unchanged, validated) ----------------
__global__ __launch_bounds__(256) void k_scores(const float* __restrict__ qkv,
                                                float* __restrict__ ws) {
  __shared__ float Us[32][68];
  __shared__ float Ws_[32][68];
  const int ms = blockIdx.z, bh = blockIdx.y;
  const int tr = blockIdx.x >> 3, tc = blockIdx.x & 7;
  const float* U; const float* Wm; float* O;
  if (ms == 0)      { U = qkv + 0 * REG; Wm = qkv + 1 * REG; O = ws + OFF_X; }
  else if (ms == 1) { U = qkv + 1 * REG; Wm = qkv + 2 * REG; O = ws + OFF_Y; }
  else              { U = qkv + 2 * REG; Wm = qkv + 0 * REG; O = ws + OFF_Z; }
  U  += bh * (NN * DD);
  Wm += bh * (NN * DD);
  O  += bh * (NN * NN);
  const int i0 = tr * 32, k0 = tc * 32;
  const int tid = threadIdx.x;
  {
    const int r = tid >> 3, d8 = (tid & 7) * 8;
    *(float4*)&Us[r][d8]      = *(const float4*)&U[(i0 + r) * DD + d8];
    *(float4*)&Us[r][d8 + 4]  = *(const float4*)&U[(i0 + r) * DD + d8 + 4];
    *(float4*)&Ws_[r][d8]     = *(const float4*)&Wm[(k0 + r) * DD + d8];
    *(float4*)&Ws_[r][d8 + 4] = *(const float4*)&Wm[(k0 + r) * DD + d8 + 4];
  }
  __syncthreads();
  const int ri = tid >> 4, ci = tid & 15;
  float a00 = 0.f, a01 = 0.f, a10 = 0.f, a11 = 0.f;
#pragma unroll
  for (int dd = 0; dd < 16; ++dd) {
    float4 u0 = *(const float4*)&Us[ri][dd * 4];
    float4 u1 = *(const float4*)&Us[ri + 16][dd * 4];
    float4 w0 = *(const float4*)&Ws_[ci][dd * 4];
    float4 w1 = *(const float4*)&Ws_[ci + 16][dd * 4];
    a00 += u0.x * w0.x + u0.y * w0.y + u0.z * w0.z + u0.w * w0.w;
    a01 += u0.x * w1.x + u0.y * w1.y + u0.z * w1.z + u0.w * w1.w;
    a10 += u1.x * w0.x + u1.y * w0.y + u1.z * w0.z + u1.w * w0.w;
    a11 += u1.x * w1.x + u1.y * w1.y + u1.z * w1.z + u1.w * w1.w;
  }
#define STORE_SC(accv, rr, cc) { \
    int row = (rr), col = (cc); \
    O[row * NN + col] = (accv) * SCALER + fminf((float)(col - row), 0.f); }
  STORE_SC(a00, i0 + ri,      k0 + ci)
  STORE_SC(a01, i0 + ri,      k0 + ci + 16)
  STORE_SC(a10, i0 + ri + 16, k0 + ci)
  STORE_SC(a11, i0 + ri + 16, k0 + ci + 16)
#undef STORE_SC
}

// ---------------- K3: all max reductions in one kernel ----------------
__global__ __launch_bounds__(256) void k_maxes(const float* __restrict__ ws,
                                               float* __restrict__ mx,
                                               float* __restrict__ yrow,
                                               float* __restrict__ mz) {
  const int blk = blockIdx.x, tid = threadIdx.x;
  if (blk < 2048) {
    const int wid = tid >> 6, lane = tid & 63;
    const float* base = ws + (blk < 1024 ? OFF_X : OFF_Y);
    float* out = (blk < 1024) ? mx : yrow;
    const int gr = (blk & 1023) * 4 + wid;
    float4 v = *(const float4*)&base[gr * 256 + lane * 4];
    float m = fmaxf(fmaxf(v.x, v.y), fmaxf(v.z, v.w));
#pragma unroll
    for (int off = 32; off; off >>= 1) m = fmaxf(m, __shfl_xor(m, off));
    if (lane == 0) out[gr] = m;
  } else {
    const int b2 = blk - 2048;            // 0..63
    const int bh = b2 >> 2, ic = b2 & 3;
    const int il = tid & 63, kp = tid >> 6;
    const int i = ic * 64 + il;
    const float* Zb = ws + OFF_Z;
    float m = -3.4e38f;
    for (int k = kp; k < 256; k += 4) m = fmaxf(m, Zb[bh * (NN * NN) + k * NN + i]);
    __shared__ float red[4][64];
    red[kp][il] = m;
    __syncthreads();
    if (kp == 0)
      mz[bh * NN + i] = fmaxf(fmaxf(red[0][il], red[1][il]), fmaxf(red[2][il], red[3][il]));
  }
}

// ---------------- K3b: reduce yrow (4096) -> my[16] ----------------
__global__ __launch_bounds__(256) void k_ymax2(const float* __restrict__ yrow, float* __restrict__ my) {
  const int bh = blockIdx.x, tid = threadIdx.x;
  float m = yrow[bh * 256 + tid];
#pragma unroll
  for (int off = 32; off; off >>= 1) m = fmaxf(m, __shfl_xor(m, off));
  __shared__ float red[4];
  if ((tid & 63) == 0) red[tid >> 6] = m;
  __syncthreads();
  if (tid == 0) my[bh] = fmaxf(fmaxf(red[0], red[1]), fmaxf(red[2], red[3]));
}

// ---------------- K4: fused exp + convert + transpose (unchanged) ----------------
__global__ __launch_bounds__(256) void k_cvtexp(float* __restrict__ ws) {
  __shared__ float T[64][65];
  const int blk = blockIdx.x, tid = threadIdx.x;
  if (blk < 256) {
    const float* X = ws + OFF_X;
    _Float16* Xh = (_Float16*)(ws + OFF_XH);
    const int gt = blk * 256 + tid;
    const int base = gt * 16;
    const float s = ws[OFF_MX + (gt >> 4)];
#pragma unroll
    for (int q = 0; q < 4; ++q) {
      float4 v = *(const float4*)&X[base + q * 4];
      f16x4 o = {(_Float16)expf(v.x - s), (_Float16)expf(v.y - s),
                 (_Float16)expf(v.z - s), (_Float16)expf(v.w - s)};
      *(f16x4*)&Xh[base + q * 4] = o;
    }
  } else if (blk < 512) {
    const int b2 = blk - 256;
    const int bh = b2 >> 4, jt = (b2 >> 2) & 3, kt = b2 & 3;
    const float* Y = ws + OFF_Y + bh * 65536;
    _Float16* Yt = (_Float16*)(ws + OFF_YT) + bh * 65536;
    const float s = ws[OFF_MY + bh];
    const int j0 = jt * 64, k0 = kt * 64;
#pragma unroll 4
    for (int p = 0; p < 16; ++p) {
      const int idx = p * 256 + tid, r = idx >> 6, c = idx & 63;
      T[r][c] = Y[(j0 + r) * 256 + k0 + c];
    }
    __syncthreads();
#pragma unroll 4
    for (int p = 0; p < 16; ++p) {
      const int idx = p * 256 + tid, r = idx >> 6, c = idx & 63;
      Yt[(k0 + r) * 256 + j0 + c] = (_Float16)expf(T[c][r] - s);
    }
  } else if (blk < 576) {
    const int b2 = blk - 512;
    const int bh = b2 >> 2, jt = b2 & 3;
    const float* v1 = ws + OFF_QKV + 3 * REG + bh * 16384;
    _Float16* v1t = (_Float16*)(ws + OFF_V1T) + bh * 16384;
    const int j0 = jt * 64;
#pragma unroll 4
    for (int p = 0; p < 16; ++p) {
      const int idx = p * 256 + tid, r = idx >> 6, c = idx & 63;
      T[r][c] = v1[(j0 + r) * 64 + c];
    }
    __syncthreads();
#pragma unroll 4
    for (int p = 0; p < 16; ++p) {
      const int idx = p * 256 + tid, r = idx >> 6, c = idx & 63;
      v1t[r * 256 + j0 + c] = (_Float16)T[c][r];
    }
  } else if (blk < 640) {
    const int b2 = blk - 576;
    const int bh = b2 >> 2, kt = b2 & 3;
    const float* v2 = ws + OFF_QKV + 4 * REG + bh * 16384;
    float* v2t = ws + OFF_V2T + bh * 16384;
    const int k0 = kt * 64;
#pragma unroll 4
    for (int p = 0; p < 16; ++p) {
      const int idx = p * 256 + tid, r = idx >> 6, c = idx & 63;
      T[r][c] = v2[(k0 + r) * 64 + c];
    }
    __syncthreads();
#pragma unroll 4
    for (int p = 0; p < 16; ++p) {
      const int idx = p * 256 + tid, r = idx >> 6, c = idx & 63;
      v2t[r * 256 + k0 + c] = T[c][r];
    }
  } else {
    const int rem = (blk - 640) * 256 + tid;
    const int bh = rem >> 14, rr = rem & 16383;
    const int c4 = (rr & 63) * 4;
    float4* base = (float4*)(ws + OFF_Z);
    float4 v = base[rem];
    float4 s = *(const float4*)&ws[OFF_MZ + bh * NN + c4];
    v.x = expf(v.x - s.x); v.y = expf(v.y - s.y); v.z = expf(v.z - s.z); v.w = expf(v.w - s.w);
    base[rem] = v;
  }
}

// ---------------- K5: MFMA triple contraction ----------------
// v4: __launch_bounds__(512, 2) -> VGPR cap 256 (was default ~80). The hoisted
// fragments (Yf 32 + Xf0 32 + Xf1 32 VGPR) + 8 acc streams need ~170 VGPR;
// at VGPR=80 the compiler spilled/rematerialized them through scratch every
// iteration, which explains the 62-63us invariance of rounds 5-7.
__global__ __launch_bounds__(512, 2) void k_heavy(const float* __restrict__ ws,
                                                  float* __restrict__ upP,
                                                  float* __restrict__ dnP) {
  const int kb = blockIdx.x, ib = blockIdx.y, zz = blockIdx.z;
  const int bh = zz >> 2, dp = zz & 3;
  const int k0 = kb * 64, i0 = ib * 64, d0 = dp * 16;
  const int tid = threadIdx.x;
  const int w = tid >> 6, lane = tid & 63;
  const int k16 = w & 3, ihalf = w >> 2;
  const int li = lane & 15, grp = lane >> 4;

  __shared__ _Float16 v1s[16 * 256];   // 8 KB
  __shared__ float v2s[16 * 64];       // 4 KB
  __shared__ float up_l[4][64][20];    // 20.5 KB
  __shared__ float dn_l[4][64];        // 1 KB

  const _Float16* Xh  = (const _Float16*)(ws + OFF_XH);
  const _Float16* Yt  = (const _Float16*)(ws + OFF_YT);
  const _Float16* v1t = (const _Float16*)(ws + OFF_V1T);
  const float*    v2t = ws + OFF_V2T;
  const float*    Zp  = ws + OFF_Z + bh * 65536;

  {
    const float4* src = (const float4*)(v1t + bh * 16384 + d0 * 256);
    ((float4*)v1s)[tid] = src[tid];
  }
  if (tid < 256) {
    const int d = tid >> 4, kq = (tid & 15) * 4;
    *(float4*)&v2s[d * 64 + kq] = *(const float4*)&v2t[bh * 16384 + (d0 + d) * 256 + k0 + kq];
  }

  f16x8 Yf[8];
  {
    const _Float16* yb = Yt + (long)bh * 65536 + (k0 + k16 * 16 + li) * 256 + grp * 8;
#pragma unroll
    for (int js = 0; js < 8; ++js) Yf[js] = *(const f16x8*)(yb + js * 32);
  }
  f16x8 Xf0[8], Xf1[8];
  {
    const _Float16* xb0 = Xh + (long)bh * 65536 + (i0 + (ihalf * 2 + 0) * 16 + li) * 256 + grp * 8;
    const _Float16* xb1 = Xh + (long)bh * 65536 + (i0 + (ihalf * 2 + 1) * 16 + li) * 256 + grp * 8;
#pragma unroll
    for (int js = 0; js < 8; ++js) { Xf0[js] = *(const f16x8*)(xb0 + js * 32); Xf1[js] = *(const f16x8*)(xb1 + js * 32); }
  }
  float Zr0[4], Zr1[4];
#pragma unroll
  for (int r = 0; r < 4; ++r) {
    const int kk = (k0 + k16 * 16 + grp * 4 + r) * 256 + i0;
    Zr0[r] = Zp[kk + (ihalf * 2 + 0) * 16 + li];
    Zr1[r] = Zp[kk + (ihalf * 2 + 1) * 16 + li];
  }

  __syncthreads();

  const int ir0 = (ihalf * 2 + 0) * 16 + li;
  const int ir1 = (ihalf * 2 + 1) * 16 + li;

  for (int it = 0; it < 16; it += 2) {
    // 8 independent accumulation streams: {d=it, d=it+1} x {i-half0, i-half1} x {js 0-3, js 4-7}
    f32x4 aA0 = {0.f,0.f,0.f,0.f}, aA1 = {0.f,0.f,0.f,0.f};  // d=it,   js0-3
    f32x4 aB0 = {0.f,0.f,0.f,0.f}, aB1 = {0.f,0.f,0.f,0.f};  // d=it,   js4-7
    f32x4 cA0 = {0.f,0.f,0.f,0.f}, cA1 = {0.f,0.f,0.f,0.f};  // d=it+1, js0-3
    f32x4 cB0 = {0.f,0.f,0.f,0.f}, cB1 = {0.f,0.f,0.f,0.f};  // d=it+1, js4-7
#pragma unroll
    for (int js = 0; js < 4; ++js) {
      f16x8 vf0 = *(const f16x8*)&v1s[it * 256 + js * 32 + grp * 8];
      f16x8 vf1 = *(const f16x8*)&v1s[(it + 1) * 256 + js * 32 + grp * 8];
      f16x8 ad0 = Yf[js] * vf0;
      f16x8 ad1 = Yf[js] * vf1;
      aA0 = __builtin_amdgcn_mfma_f32_16x16x32_f16(ad0, Xf0[js], aA0, 0, 0, 0);
      aA1 = __builtin_amdgcn_mfma_f32_16x16x32_f16(ad0, Xf1[js], aA1, 0, 0, 0);
      cA0 = __builtin_amdgcn_mfma_f32_16x16x32_f16(ad1, Xf0[js], cA0, 0, 0, 0);
      cA1 = __builtin_amdgcn_mfma_f32_16x16x32_f16(ad1, Xf1[js], cA1, 0, 0, 0);
    }
#pragma unroll
    for (int js = 4; js < 8; ++js) {
      f16x8 vf0 = *(const f16x8*)&v1s[it * 256 + js * 32 + grp * 8];
      f16x8 vf1 = *(const f16x8*)&v1s[(it + 1) * 256 + js * 32 + grp * 8];
      f16x8 ad0 = Yf[js] * vf0;
      f16x8 ad1 = Yf[js] * vf1;
      aB0 = __builtin_amdgcn_mfma_f32_16x16x32_f16(ad0, Xf0[js], aB0, 0, 0, 0);
      aB1 = __builtin_amdgcn_mfma_f32_16x16x32_f16(ad0, Xf1[js], aB1, 0, 0, 0);
      cB0 = __builtin_amdgcn_mfma_f32_16x16x32_f16(ad1, Xf0[js], cB0, 0, 0, 0);
      cB1 = __builtin_amdgcn_mfma_f32_16x16x32_f16(ad1, Xf1[js], cB1, 0, 0, 0);
    }
    f32x4 acc0 = aA0 + aB0, acc1 = aA1 + aB1;   // d=it
    f32x4 dcc0 = cA0 + cB0, dcc1 = cA1 + cB1;   // d=it+1
    {
      f32x4 w2 = *(const f32x4*)&v2s[it * 64 + k16 * 16 + grp * 4];
      float s0 = (acc0[0] * Zr0[0]) * w2[0] + (acc0[1] * Zr0[1]) * w2[1]
               + (acc0[2] * Zr0[2]) * w2[2] + (acc0[3] * Zr0[3]) * w2[3];
      float s1 = (acc1[0] * Zr1[0]) * w2[0] + (acc1[1] * Zr1[1]) * w2[1]
               + (acc1[2] * Zr1[2]) * w2[2] + (acc1[3] * Zr1[3]) * w2[3];
      s0 += __shfl_xor(s0, 16); s0 += __shfl_xor(s0, 32);
      s1 += __shfl_xor(s1, 16); s1 += __shfl_xor(s1, 32);
      if (lane < 16) {
        up_l[k16][ir0][it] = s0;
        up_l[k16][ir1][it] = s1;
      }
    }
    {
      f32x4 w2 = *(const f32x4*)&v2s[(it + 1) * 64 + k16 * 16 + grp * 4];
      float s0 = (dcc0[0] * Zr0[0]) * w2[0] + (dcc0[1] * Zr0[1]) * w2[1]
               + (dcc0[2] * Zr0[2]) * w2[2] + (dcc0[3] * Zr0[3]) * w2[3];
      float s1 = (dcc1[0] * Zr1[0]) * w2[0] + (dcc1[1] * Zr1[1]) * w2[1]
               + (dcc1[2] * Zr1[2]) * w2[2] + (dcc1[3] * Zr1[3]) * w2[3];
      s0 += __shfl_xor(s0, 16); s0 += __shfl_xor(s0, 32);
      s1 += __shfl_xor(s1, 16); s1 += __shfl_xor(s1, 32);
      if (lane < 16) {
        up_l[k16][ir0][it + 1] = s0;
        up_l[k16][ir1][it + 1] = s1;
      }
    }
  }
  if (dp == 3) { // down slot: A = Y (v1 == 1), v2 == 1; 4 streams
    f32x4 aA0 = {0.f,0.f,0.f,0.f}, aA1 = {0.f,0.f,0.f,0.f};
    f32x4 aB0 = {0.f,0.f,0.f,0.f}, aB1 = {0.f,0.f,0.f,0.f};
#pragma unroll
    for (int js = 0; js < 4; ++js) {
      aA0 = __builtin_amdgcn_mfma_f32_16x16x32_f16(Yf[js], Xf0[js], aA0, 0, 0, 0);
      aA1 = __builtin_amdgcn_mfma_f32_16x16x32_f16(Yf[js], Xf1[js], aA1, 0, 0, 0);
      aB0 = __builtin_amdgcn_mfma_f32_16x16x32_f16(Yf[js + 4], Xf0[js + 4], aB0, 0, 0, 0);
      aB1 = __builtin_amdgcn_mfma_f32_16x16x32_f16(Yf[js + 4], Xf1[js + 4], aB1, 0, 0, 0);
    }
    f32x4 acc0 = aA0 + aB0, acc1 = aA1 + aB1;
    float s0 = acc0[0] * Zr0[0] + acc0[1] * Zr0[1] + acc0[2] * Zr0[2] + acc0[3] * Zr0[3];
    float s1 = acc1[0] * Zr1[0] + acc1[1] * Zr1[1] + acc1[2] * Zr1[2] + acc1[3] * Zr1[3];
    s0 += __shfl_xor(s0, 16); s0 += __shfl_xor(s0, 32);
    s1 += __shfl_xor(s1, 16); s1 += __shfl_xor(s1, 32);
    if (lane < 16) {
      dn_l[k16][ir0] = s0;
      dn_l[k16][ir1] = s1;
    }
  }
  __syncthreads();
  {
    const int il = tid >> 3, dq = (tid & 7) * 2;
    float a = up_l[0][il][dq]     + up_l[1][il][dq]     + up_l[2][il][dq]     + up_l[3][il][dq];
    float b = up_l[0][il][dq + 1] + up_l[1][il][dq + 1] + up_l[2][il][dq + 1] + up_l[3][il][dq + 1];
    float* dst = upP + ((long)((kb * 16 + bh) * 256) + i0 + il) * 64 + d0 + dq;
    dst[0] = a; dst[1] = b;
  }
  if (dp == 3 && tid < 64)
    dnP[(kb * 16 + bh) * 256 + i0 + tid] =
        dn_l[0][tid] + dn_l[1][tid] + dn_l[2][tid] + dn_l[3][tid];
}

// ---------------- K6: combine 4 k-partials, divide, write [b][n][h*64+d] ----------------
__global__ __launch_bounds__(256) void k_final(const float* __restrict__ ws_in, float* __restrict__ out) {
  const int g = blockIdx.x * 256 + threadIdx.x;
  const int e0 = g * 4;
  const int c = e0 & 511, n = (e0 >> 9) & 255, b = e0 >> 17;
  const int h = c >> 6, d = c & 63;
  const int bh = b * 8 + h;
  const float* upP = ws_in + OFF_UP;
  const float* dnP = ws_in + OFF_DN;
  float4 acc = make_float4(0.f, 0.f, 0.f, 0.f);
  float dn = 0.f;
#pragma unroll
  for (int ks = 0; ks < KB; ++ks) {
    const float4 u = *(const float4*)&upP[((ks * 16 + bh) * 256 + n) * 64 + d];
    acc.x += u.x; acc.y += u.y; acc.z += u.z; acc.w += u.w;
    dn += dnP[(ks * 16 + bh) * 256 + n];
  }
  const float inv = 1.f / (dn + 1e-9f);
  acc.x *= inv; acc.y *= inv; acc.z *= inv; acc.w *= inv;
  *(float4*)&out[e0] = acc;
}

extern "C" void kernel_launch(void* const* d_in, const int* in_sizes, int n_in,
                              void* d_out, int out_size, void* d_ws, size_t ws_size,
                              hipStream_t stream) {
  (void)in_sizes; (void)n_in; (void)out_size; (void)ws_size;
  const float* hidden = (const float*)d_in[0];
  const float* W      = (const float*)d_in[1];
  float* ws  = (float*)d_ws;
  float* out = (float*)d_out;

  k_proj<<<dim3(40, 8), 256, 0, stream>>>(hidden, W, ws + OFF_QKV);
  k_scores<<<dim3(64, BH, 3), 256, 0, stream>>>(ws + OFF_QKV, ws);
  k_maxes<<<dim3(2112), 256, 0, stream>>>(ws, ws + OFF_MX, ws + OFF_YR, ws + OFF_MZ);
  k_ymax2<<<dim3(16), 256, 0, stream>>>(ws + OFF_YR, ws + OFF_MY);
  k_cvtexp<<<dim3(1664), 256, 0, stream>>>(ws);
  k_heavy<<<dim3(KB, 4, 64), 512, 0, stream>>>(ws, ws + OFF_UP, ws + OFF_DN);
  k_final<<<dim3(256), 256, 0, stream>>>(ws, out);
}